// Round 3
// baseline (2303.711 us; speedup 1.0000x reference)
//
#include <hip/hip_runtime.h>

using u16 = unsigned short;
using u32 = unsigned int;
typedef __attribute__((ext_vector_type(8))) short s16x8;
typedef __attribute__((ext_vector_type(4))) float f32x4;

// may_alias types for all type-punned memory access (removes strict-aliasing UB)
typedef uint4  __attribute__((may_alias)) uint4a;
typedef ushort4 __attribute__((may_alias)) ushort4a;
typedef float4 __attribute__((may_alias)) float4a;
typedef u16    __attribute__((may_alias)) u16a;
typedef s16x8  __attribute__((may_alias)) s16x8a;

#define D_ 1024
#define H_ 4
#define B_ 4
#define S_ 2048
#define M_ 8192  /* B_*S_ */

#define BM 128
#define BN 128
#define BK 32

__device__ __forceinline__ float bf2f(u16 u) { return __uint_as_float(((u32)u) << 16); }
__device__ __forceinline__ u16 f2bf(float f) {
  u32 b = __float_as_uint(f);
  return (u16)((b + 0x7fffu + ((b >> 16) & 1u)) >> 16);
}

// ---------------- f32 -> bf16 convert (n divisible by 4) ----------------
__global__ __launch_bounds__(256) void cvt_f32_bf16(const float* __restrict__ in,
                                                    u16* __restrict__ out, long n4) {
  long stride = (long)gridDim.x * blockDim.x;
  for (long i = (long)blockIdx.x * blockDim.x + threadIdx.x; i < n4; i += stride) {
    float4 v = ((const float4a*)in)[i];
    ushort4 o;
    o.x = f2bf(v.x); o.y = f2bf(v.y); o.z = f2bf(v.z); o.w = f2bf(v.w);
    ((ushort4a*)out)[i] = o;
  }
}

// ---------------- tiled MFMA GEMM ----------------
// C[z] = A[z] @ B[z] * scale (+ bias[z]) (+= existing C if ACC)
// A: [M,K] bf16 row-major (lda). BT=1: B is [N,K] row-major (ldb = K-stride).
// BT=0: B is [K,N] row-major (ldb = N-stride), transposed while staging to LDS.
// C element index = (z/c_div)*c_str1 + (z%c_div)*c_str2 + m*ldc + n.
__device__ __forceinline__ int lds_slot(int row, int ks) {
  return row * 4 + (ks ^ ((row >> 1) & 3));  // 16B-granular XOR swizzle
}

template <int BT, int OUT_BF16, int HAS_BIAS, int ACC>
__global__ __launch_bounds__(256, 2) void gemm128(
    const u16* __restrict__ A, const u16* __restrict__ Bm, void* __restrict__ Cp,
    const float* __restrict__ bias, int K, int lda, int ldb, int ldc,
    long sA, long sB, long sBias, int c_div, long c_str1, long c_str2, float scale) {
  __shared__ u16 Al[BM * BK];
  __shared__ u16 Bl[BN * BK];
  const int z = blockIdx.z;
  A += (long)z * sA;
  Bm += (long)z * sB;
  const long coff = (long)(z / c_div) * c_str1 + (long)(z % c_div) * c_str2;
  const int bm = blockIdx.y * BM, bn = blockIdx.x * BN;
  const int tid = threadIdx.x;
  const int lane = tid & 63;
  const int w = tid >> 6;
  const int wr = w >> 1, wc = w & 1;
  f32x4 acc[4][4] = {};

  for (int k0 = 0; k0 < K; k0 += BK) {
    __syncthreads();
    // stage A tile: rows bm..bm+127, cols k0..k0+31 (8 bf16 = 16B per chunk)
#pragma unroll
    for (int it = 0; it < 2; ++it) {
      int c = tid + it * 256;
      int row = c >> 2, j = c & 3;
      uint4 val = *(const uint4a*)(A + (long)(bm + row) * lda + (k0 + j * 8));
      *(uint4a*)&Al[lds_slot(row, j) * 8] = val;
    }
    if (BT) {
#pragma unroll
      for (int it = 0; it < 2; ++it) {
        int c = tid + it * 256;
        int row = c >> 2, j = c & 3;
        uint4 val = *(const uint4a*)(Bm + (long)(bn + row) * ldb + (k0 + j * 8));
        *(uint4a*)&Bl[lds_slot(row, j) * 8] = val;
      }
    } else {
      // B is [K,N]: read 8 along n (coalesced), scatter-transpose into Bl[n][k]
#pragma unroll
      for (int it = 0; it < 2; ++it) {
        int kk = it * 16 + (tid >> 4);  // 0..31
        int n0 = (tid & 15) * 8;
        uint4 val = *(const uint4a*)(Bm + (long)(k0 + kk) * ldb + (bn + n0));
        ushort4 lo, hi;
        lo.x = (u16)(val.x & 0xffff); lo.y = (u16)(val.x >> 16);
        lo.z = (u16)(val.y & 0xffff); lo.w = (u16)(val.y >> 16);
        hi.x = (u16)(val.z & 0xffff); hi.y = (u16)(val.z >> 16);
        hi.z = (u16)(val.w & 0xffff); hi.w = (u16)(val.w >> 16);
        u16 pv[8] = {lo.x, lo.y, lo.z, lo.w, hi.x, hi.y, hi.z, hi.w};
#pragma unroll
        for (int jj = 0; jj < 8; ++jj) {
          Bl[lds_slot(n0 + jj, kk >> 3) * 8 + (kk & 7)] = pv[jj];
        }
      }
    }
    __syncthreads();
    const int ks = lane >> 4;
    s16x8 a[4], b[4];
#pragma unroll
    for (int i = 0; i < 4; i++) {
      int row = wr * 64 + i * 16 + (lane & 15);
      a[i] = *(const s16x8a*)&Al[lds_slot(row, ks) * 8];
    }
#pragma unroll
    for (int j = 0; j < 4; j++) {
      int row = wc * 64 + j * 16 + (lane & 15);
      b[j] = *(const s16x8a*)&Bl[lds_slot(row, ks) * 8];
    }
#pragma unroll
    for (int i = 0; i < 4; i++)
#pragma unroll
      for (int j = 0; j < 4; j++)
        acc[i][j] = __builtin_amdgcn_mfma_f32_16x16x32_bf16(a[i], b[j], acc[i][j], 0, 0, 0);
  }

  // epilogue: C/D layout col = lane&15, row = (lane>>4)*4 + reg
#pragma unroll
  for (int i = 0; i < 4; i++) {
    int mbase = bm + wr * 64 + i * 16 + ((lane >> 4) << 2);
#pragma unroll
    for (int j = 0; j < 4; j++) {
      int n = bn + wc * 64 + j * 16 + (lane & 15);
      float bv = 0.f;
      if (HAS_BIAS) bv = bias[(long)z * sBias + n];
#pragma unroll
      for (int r = 0; r < 4; r++) {
        float v = acc[i][j][r] * scale + bv;
        long idx = coff + (long)(mbase + r) * ldc + n;
        if (OUT_BF16) {
          ((u16a*)Cp)[idx] = f2bf(v);
        } else {
          float* Cf = (float*)Cp;
          Cf[idx] = ACC ? (Cf[idx] + v) : v;
        }
      }
    }
  }
}

// ---------------- row softmax over 2048 bf16, OUT OF PLACE ----------------
__global__ __launch_bounds__(256) void softmax2048(const u16* __restrict__ Sin,
                                                   u16* __restrict__ Pout) {
  const long row = blockIdx.x;
  const int t = threadIdx.x, lane = t & 63, w = t >> 6;
  uint4 raw = *(const uint4a*)(Sin + row * 2048 + t * 8);
  u16 u[8];
  u[0] = (u16)(raw.x & 0xffff); u[1] = (u16)(raw.x >> 16);
  u[2] = (u16)(raw.y & 0xffff); u[3] = (u16)(raw.y >> 16);
  u[4] = (u16)(raw.z & 0xffff); u[5] = (u16)(raw.z >> 16);
  u[6] = (u16)(raw.w & 0xffff); u[7] = (u16)(raw.w >> 16);
  float v[8], mx = -3.4e38f;
#pragma unroll
  for (int j = 0; j < 8; j++) { v[j] = bf2f(u[j]); mx = fmaxf(mx, v[j]); }
#pragma unroll
  for (int o = 32; o > 0; o >>= 1) mx = fmaxf(mx, __shfl_xor(mx, o, 64));
  __shared__ float red[4];
  if (lane == 0) red[w] = mx;
  __syncthreads();
  mx = fmaxf(fmaxf(red[0], red[1]), fmaxf(red[2], red[3]));
  float s = 0.f;
#pragma unroll
  for (int j = 0; j < 8; j++) { v[j] = __expf(v[j] - mx); s += v[j]; }
#pragma unroll
  for (int o = 32; o > 0; o >>= 1) s += __shfl_xor(s, o, 64);
  __syncthreads();
  if (lane == 0) red[w] = s;
  __syncthreads();
  float inv = 1.f / (red[0] + red[1] + red[2] + red[3]);
  uint4 ow;
  u32 w0 = f2bf(v[0] * inv) | ((u32)f2bf(v[1] * inv) << 16);
  u32 w1 = f2bf(v[2] * inv) | ((u32)f2bf(v[3] * inv) << 16);
  u32 w2 = f2bf(v[4] * inv) | ((u32)f2bf(v[5] * inv) << 16);
  u32 w3 = f2bf(v[6] * inv) | ((u32)f2bf(v[7] * inv) << 16);
  ow.x = w0; ow.y = w1; ow.z = w2; ow.w = w3;
  *(uint4a*)(Pout + row * 2048 + t * 8) = ow;
}

// ---------------- LayerNorm over 1024: Y = LN(X+R)*g+be; optional bf16 copy ----------------
__global__ __launch_bounds__(256) void ln_kernel(
    const float* __restrict__ X, const float* __restrict__ R,
    const float* __restrict__ g, const float* __restrict__ be,
    float* __restrict__ Y, u16* __restrict__ Yb) {
  const long row = blockIdx.x;
  const int t = threadIdx.x, lane = t & 63, w = t >> 6;
  const long base = row * 1024 + t * 4;
  float4 a = *(const float4a*)(X + base);
  float4 b = *(const float4a*)(R + base);
  float v0 = a.x + b.x, v1 = a.y + b.y, v2 = a.z + b.z, v3 = a.w + b.w;
  float s = v0 + v1 + v2 + v3;
  float q = v0 * v0 + v1 * v1 + v2 * v2 + v3 * v3;
#pragma unroll
  for (int o = 32; o > 0; o >>= 1) { s += __shfl_xor(s, o, 64); q += __shfl_xor(q, o, 64); }
  __shared__ float rs[4], rq[4];
  if (lane == 0) { rs[w] = s; rq[w] = q; }
  __syncthreads();
  s = rs[0] + rs[1] + rs[2] + rs[3];
  q = rq[0] + rq[1] + rq[2] + rq[3];
  const float mu = s * (1.f / 1024.f);
  const float var = q * (1.f / 1024.f) - mu * mu;
  const float rstd = rsqrtf(var + 1e-5f);
  float4 gv = *(const float4a*)(g + t * 4);
  float4 bv = *(const float4a*)(be + t * 4);
  float o0 = (v0 - mu) * rstd * gv.x + bv.x;
  float o1 = (v1 - mu) * rstd * gv.y + bv.y;
  float o2 = (v2 - mu) * rstd * gv.z + bv.z;
  float o3 = (v3 - mu) * rstd * gv.w + bv.w;
  float4 o4; o4.x = o0; o4.y = o1; o4.z = o2; o4.w = o3;
  *(float4a*)(Y + base) = o4;
  if (Yb) {
    ushort4 ob; ob.x = f2bf(o0); ob.y = f2bf(o1); ob.z = f2bf(o2); ob.w = f2bf(o3);
    *(ushort4a*)(Yb + base) = ob;
  }
}

extern "C" void kernel_launch(void* const* d_in, const int* in_sizes, int n_in,
                              void* d_out, int out_size, void* d_ws, size_t ws_size,
                              hipStream_t stream) {
  const float* x   = (const float*)d_in[0];
  const float* Wq  = (const float*)d_in[1];
  const float* bq  = (const float*)d_in[2];
  const float* Wk  = (const float*)d_in[3];
  const float* bk  = (const float*)d_in[4];
  const float* Wv  = (const float*)d_in[5];
  const float* bv  = (const float*)d_in[6];
  const float* W1  = (const float*)d_in[7];
  const float* b1  = (const float*)d_in[8];
  const float* g1  = (const float*)d_in[9];
  const float* be1 = (const float*)d_in[10];
  const float* W2  = (const float*)d_in[11];
  const float* b2  = (const float*)d_in[12];
  const float* g2  = (const float*)d_in[13];
  const float* be2 = (const float*)d_in[14];
  float* out = (float*)d_out;

  // ---- workspace layout (bytes). Peak 186,646,528 B (~178 MiB).
  const size_t NEED = 186646528ULL;
  if (ws_size < NEED) return;
  char* ws = (char*)d_ws;
  u16* xb  = (u16*)(ws + 0L);           // 16,777,216  [M][D]
  u16* Wqb = (u16*)(ws + 16777216L);    //  8,388,608  [H][D][D]
  u16* Wkb = (u16*)(ws + 25165824L);    //  8,388,608
  u16* Wvb = (u16*)(ws + 33554432L);    //  8,388,608
  u16* W1b = (u16*)(ws + 41943040L);    //  8,388,608  [H*D][D]
  u16* W2b = (u16*)(ws + 50331648L);    //  2,097,152  [D][D]
  u16* Qh  = (u16*)(ws + 52428800L);    // 16,777,216  [M][D] (per-head)
  u16* Kh  = (u16*)(ws + 69206016L);    // 16,777,216
  u16* Vh  = (u16*)(ws + 85983232L);    // 16,777,216
  u16* Ch  = (u16*)(ws + 102760448L);   // 16,777,216  per-head attn out
  float* proj = (float*)(ws + 119537664L); // 33,554,432 f32, accumulated over heads
  u16* Sbh = (u16*)(ws + 153092096L);   // 33,554,432  [B][S][S] per-head raw scores
  // P (softmax out) aliases Qh+Kh: Qh/Kh dead after score GEMM, rewritten next head
  u16* Pb  = Qh;                        // 33,554,432  [B][S][S]
  // aliases over dead regions (valid after the head loop):
  float* y  = (float*)Qh;               // 33.5 MB f32 (covers Qh+Kh, dead)
  u16*   yb = Vh;                       // 16.8 MB bf16 (Vh dead)
  float* z2 = proj;                     // 33.5 MB f32 (proj dead after LN1)

  dim3 blk(256);
  // ---- converts
  auto cvt = [&](const float* in, u16* o, long n) {
    long n4 = n / 4;
    int blocks = (int)((n4 + 255) / 256);
    if (blocks > 4096) blocks = 4096;
    hipLaunchKernelGGL(cvt_f32_bf16, dim3(blocks), blk, 0, stream, in, o, n4);
  };
  cvt(x, xb, (long)M_ * D_);
  cvt(Wq, Wqb, (long)H_ * D_ * D_);
  cvt(Wk, Wkb, (long)H_ * D_ * D_);
  cvt(Wv, Wvb, (long)H_ * D_ * D_);
  cvt(W1, W1b, 4096L * 1024L);
  cvt(W2, W2b, 1024L * 1024L);

  dim3 gproj(D_ / BN, M_ / BM, 1);           // 8 x 64
  dim3 gsc(S_ / BN, S_ / BM, B_);            // 16 x 16 x 4
  dim3 gpv(D_ / BN, S_ / BM, B_);            // 8 x 16 x 4

  for (int h = 0; h < H_; ++h) {
    const long wo = (long)h * D_ * D_;
    // Q/K/V for this head: [M][D] bf16
    hipLaunchKernelGGL((gemm128<0, 1, 1, 0>), gproj, blk, 0, stream,
                       xb, Wqb + wo, (void*)Qh, bq + (long)h * D_, D_, D_, D_, D_,
                       0L, 0L, 0L, 1, 0L, 0L, 1.0f);
    hipLaunchKernelGGL((gemm128<0, 1, 1, 0>), gproj, blk, 0, stream,
                       xb, Wkb + wo, (void*)Kh, bk + (long)h * D_, D_, D_, D_, D_,
                       0L, 0L, 0L, 1, 0L, 0L, 1.0f);
    hipLaunchKernelGGL((gemm128<0, 1, 1, 0>), gproj, blk, 0, stream,
                       xb, Wvb + wo, (void*)Vh, bv + (long)h * D_, D_, D_, D_, D_,
                       0L, 0L, 0L, 1, 0L, 0L, 1.0f);
    // scores: per b, Sbh[b] = Q[b] @ K[b]^T / 32  (bf16)
    hipLaunchKernelGGL((gemm128<1, 1, 0, 0>), gsc, blk, 0, stream,
                       Qh, Kh, (void*)Sbh, (const float*)nullptr, D_, D_, D_, S_,
                       (long)S_ * D_, (long)S_ * D_, 0L, 1, (long)S_ * S_, 0L, 0.03125f);
    // softmax rows: Pb = softmax(Sbh)   (Pb aliases Qh+Kh, both dead now)
    hipLaunchKernelGGL(softmax2048, dim3(B_ * S_), blk, 0, stream, Sbh, Pb);
    // PV: Ch[b] = P[b] @ V[b]  (bf16)
    hipLaunchKernelGGL((gemm128<0, 1, 0, 0>), gpv, blk, 0, stream,
                       Pb, Vh, (void*)Ch, (const float*)nullptr, S_, S_, D_, D_,
                       (long)S_ * S_, (long)S_ * D_, 0L, 1, (long)S_ * D_, 0L, 1.0f);
    // proj (+)= Ch @ W1[h*D:(h+1)*D, :]  (+ b1 on first head)
    if (h == 0) {
      hipLaunchKernelGGL((gemm128<0, 0, 1, 0>), gproj, blk, 0, stream,
                         Ch, W1b + (long)h * D_ * D_, (void*)proj, b1, D_, D_, D_, D_,
                         0L, 0L, 0L, 1, 0L, 0L, 1.0f);
    } else {
      hipLaunchKernelGGL((gemm128<0, 0, 0, 1>), gproj, blk, 0, stream,
                         Ch, W1b + (long)h * D_ * D_, (void*)proj, (const float*)nullptr,
                         D_, D_, D_, D_, 0L, 0L, 0L, 1, 0L, 0L, 1.0f);
    }
  }

  // ---- LN1: y = LN(x + proj); also bf16 copy yb
  hipLaunchKernelGGL(ln_kernel, dim3(M_), blk, 0, stream, x, proj, g1, be1, y, yb);

  // ---- W2: z2 = yb @ W2 + b2 (f32)  (z2 aliases proj, dead after LN1)
  hipLaunchKernelGGL((gemm128<0, 0, 1, 0>), gproj, blk, 0, stream,
                     yb, W2b, (void*)z2, b2, D_, D_, D_, D_,
                     0L, 0L, 0L, 1, 0L, 0L, 1.0f);

  // ---- LN2: out = LN(y + z2)
  hipLaunchKernelGGL(ln_kernel, dim3(M_), blk, 0, stream, y, z2, g2, be2, out, (u16*)nullptr);
}

// Round 4
// 1047.709 us; speedup vs baseline: 2.1988x; 2.1988x over previous
//
#include <hip/hip_runtime.h>

using u16 = unsigned short;
using u32 = unsigned int;
typedef __attribute__((ext_vector_type(8))) short s16x8;
typedef __attribute__((ext_vector_type(4))) float f32x4;

typedef uint4   __attribute__((may_alias)) uint4a;
typedef ushort4 __attribute__((may_alias)) ushort4a;
typedef float4  __attribute__((may_alias)) float4a;
typedef u16     __attribute__((may_alias)) u16a;
typedef s16x8   __attribute__((may_alias)) s16x8a;

#define D_ 1024
#define H_ 4
#define B_ 4
#define S_ 2048
#define M_ 8192  /* B_*S_ */

#define BM 128
#define BN 128
#define BK 32

__device__ __forceinline__ float bf2f(u16 u) { return __uint_as_float(((u32)u) << 16); }
__device__ __forceinline__ u16 f2bf(float f) {
  u32 b = __float_as_uint(f);
  return (u16)((b + 0x7fffu + ((b >> 16) & 1u)) >> 16);
}

// async global->LDS, 16B per lane. LDS dest is wave-uniform base + lane*16;
// global src is per-lane.
__device__ __forceinline__ void gload_lds16(const u16* g, u16* l) {
  __builtin_amdgcn_global_load_lds(
      (const __attribute__((address_space(1))) void*)g,
      (__attribute__((address_space(3))) void*)l, 16, 0, 0);
}

// ---------------- f32 -> bf16 convert (n divisible by 4) ----------------
__global__ __launch_bounds__(256) void cvt_f32_bf16(const float* __restrict__ in,
                                                    u16* __restrict__ out, long n4) {
  long stride = (long)gridDim.x * blockDim.x;
  for (long i = (long)blockIdx.x * blockDim.x + threadIdx.x; i < n4; i += stride) {
    float4 v = ((const float4a*)in)[i];
    ushort4 o;
    o.x = f2bf(v.x); o.y = f2bf(v.y); o.z = f2bf(v.z); o.w = f2bf(v.w);
    ((ushort4a*)out)[i] = o;
  }
}

// ------------- transpose-convert: out[z][n][k] = bf16(in[z][k][n]) -------------
__global__ __launch_bounds__(256) void tcvt(const float* __restrict__ in,
                                            u16* __restrict__ out, int K, int N,
                                            long s_in, long s_out) {
  __shared__ float t[32][33];
  const int z = blockIdx.z;
  in += (long)z * s_in;
  out += (long)z * s_out;
  const int n0 = blockIdx.x * 32, k0 = blockIdx.y * 32;
  const int tx = threadIdx.x & 31, ty = threadIdx.x >> 5;  // ty 0..7
#pragma unroll
  for (int i = 0; i < 32; i += 8) t[ty + i][tx] = in[(long)(k0 + ty + i) * N + n0 + tx];
  __syncthreads();
#pragma unroll
  for (int i = 0; i < 32; i += 8)
    out[(long)(n0 + ty + i) * K + k0 + tx] = f2bf(t[tx][ty + i]);
}

// ---------------- tiled MFMA GEMM, B^T only ----------------
// C[z] = A[z] @ B[z]^T * scale (+ bias) (+= C if ACC)
// A: [M,K] bf16 (lda). B: [N,K] bf16 (ldb).
// OUT_MODE: 0 = f32 (ACC/bias ok), 1 = bf16, 2 = bf16 transposed-per-batch
//           (idx = (m>>11)*D_*S_ + n*S_ + (m&2047)) for V^T production.
// LDS: 16B chunks; chunk (row, j) lives at slot row*4 + (j ^ ((row>>1)&3)).
// Staged with global_load_lds: linear LDS slots, inverse-swizzled global src.
__device__ __forceinline__ int lds_slot(int row, int ks) {
  return row * 4 + (ks ^ ((row >> 1) & 3));
}

template <int OUT_MODE, int HAS_BIAS, int ACC>
__global__ __launch_bounds__(256, 2) void gemm_bt(
    const u16* __restrict__ A, const u16* __restrict__ Bm, void* __restrict__ Cp,
    const float* __restrict__ bias, int K, int lda, int ldb, int ldc,
    long sA, long sB, long sC, float scale) {
  __shared__ u16 Al[BM * BK];
  __shared__ u16 Bl[BN * BK];
  const int z = blockIdx.z;
  A += (long)z * sA;
  Bm += (long)z * sB;
  const long coff = (long)z * sC;
  const int bm = blockIdx.y * BM, bn = blockIdx.x * BN;
  const int tid = threadIdx.x;
  const int lane = tid & 63;
  const int w = tid >> 6;
  const int wr = w >> 1, wc = w & 1;
  f32x4 acc[4][4] = {};

  for (int k0 = 0; k0 < K; k0 += BK) {
    __syncthreads();
    // stage A and B tiles: 512 slots each; wave w fills slots [w*128, w*128+128)
#pragma unroll
    for (int it = 0; it < 2; ++it) {
      const int sbase = w * 128 + it * 64;
      const int slot = sbase + lane;
      const int row = slot >> 2;
      const int j = (slot & 3) ^ ((row >> 1) & 3);  // inverse swizzle on global src
      gload_lds16(A + (long)(bm + row) * lda + (k0 + j * 8), &Al[sbase * 8]);
      gload_lds16(Bm + (long)(bn + row) * ldb + (k0 + j * 8), &Bl[sbase * 8]);
    }
    __syncthreads();  // compiler drains vmcnt before this barrier
    const int ks = lane >> 4;
    s16x8 a[4], b[4];
#pragma unroll
    for (int i = 0; i < 4; i++) {
      int row = wr * 64 + i * 16 + (lane & 15);
      a[i] = *(const s16x8a*)&Al[lds_slot(row, ks) * 8];
    }
#pragma unroll
    for (int j = 0; j < 4; j++) {
      int row = wc * 64 + j * 16 + (lane & 15);
      b[j] = *(const s16x8a*)&Bl[lds_slot(row, ks) * 8];
    }
#pragma unroll
    for (int i = 0; i < 4; i++)
#pragma unroll
      for (int j = 0; j < 4; j++)
        acc[i][j] = __builtin_amdgcn_mfma_f32_16x16x32_bf16(a[i], b[j], acc[i][j], 0, 0, 0);
  }

  // epilogue: C/D layout col = lane&15, row = (lane>>4)*4 + reg
#pragma unroll
  for (int i = 0; i < 4; i++) {
    int mbase = bm + wr * 64 + i * 16 + ((lane >> 4) << 2);
#pragma unroll
    for (int j = 0; j < 4; j++) {
      int n = bn + wc * 64 + j * 16 + (lane & 15);
      float bv = 0.f;
      if (HAS_BIAS) bv = bias[n];
#pragma unroll
      for (int r = 0; r < 4; r++) {
        float v = acc[i][j][r] * scale + bv;
        int mm = mbase + r;
        if (OUT_MODE == 2) {
          long idx = (long)(mm >> 11) * ((long)D_ * S_) + (long)n * S_ + (mm & 2047);
          ((u16a*)Cp)[idx] = f2bf(v);
        } else {
          long idx = coff + (long)mm * ldc + n;
          if (OUT_MODE == 1) {
            ((u16a*)Cp)[idx] = f2bf(v);
          } else {
            float* Cf = (float*)Cp;
            Cf[idx] = ACC ? (Cf[idx] + v) : v;
          }
        }
      }
    }
  }
}

// ---------------- row softmax over 2048 bf16, out of place ----------------
__global__ __launch_bounds__(256) void softmax2048(const u16* __restrict__ Sin,
                                                   u16* __restrict__ Pout) {
  const long row = blockIdx.x;
  const int t = threadIdx.x, lane = t & 63, w = t >> 6;
  uint4 raw = *(const uint4a*)(Sin + row * 2048 + t * 8);
  u16 u[8];
  u[0] = (u16)(raw.x & 0xffff); u[1] = (u16)(raw.x >> 16);
  u[2] = (u16)(raw.y & 0xffff); u[3] = (u16)(raw.y >> 16);
  u[4] = (u16)(raw.z & 0xffff); u[5] = (u16)(raw.z >> 16);
  u[6] = (u16)(raw.w & 0xffff); u[7] = (u16)(raw.w >> 16);
  float v[8], mx = -3.4e38f;
#pragma unroll
  for (int j = 0; j < 8; j++) { v[j] = bf2f(u[j]); mx = fmaxf(mx, v[j]); }
#pragma unroll
  for (int o = 32; o > 0; o >>= 1) mx = fmaxf(mx, __shfl_xor(mx, o, 64));
  __shared__ float red[4];
  if (lane == 0) red[w] = mx;
  __syncthreads();
  mx = fmaxf(fmaxf(red[0], red[1]), fmaxf(red[2], red[3]));
  float s = 0.f;
#pragma unroll
  for (int j = 0; j < 8; j++) { v[j] = __expf(v[j] - mx); s += v[j]; }
#pragma unroll
  for (int o = 32; o > 0; o >>= 1) s += __shfl_xor(s, o, 64);
  __syncthreads();
  if (lane == 0) red[w] = s;
  __syncthreads();
  float inv = 1.f / (red[0] + red[1] + red[2] + red[3]);
  uint4 ow;
  ow.x = f2bf(v[0] * inv) | ((u32)f2bf(v[1] * inv) << 16);
  ow.y = f2bf(v[2] * inv) | ((u32)f2bf(v[3] * inv) << 16);
  ow.z = f2bf(v[4] * inv) | ((u32)f2bf(v[5] * inv) << 16);
  ow.w = f2bf(v[6] * inv) | ((u32)f2bf(v[7] * inv) << 16);
  *(uint4a*)(Pout + row * 2048 + t * 8) = ow;
}

// ---------------- LayerNorm over 1024: Y = LN(X+R)*g+be; optional bf16 copy ----------------
__global__ __launch_bounds__(256) void ln_kernel(
    const float* __restrict__ X, const float* __restrict__ R,
    const float* __restrict__ g, const float* __restrict__ be,
    float* __restrict__ Y, u16* __restrict__ Yb) {
  const long row = blockIdx.x;
  const int t = threadIdx.x, lane = t & 63, w = t >> 6;
  const long base = row * 1024 + t * 4;
  float4 a = *(const float4a*)(X + base);
  float4 b = *(const float4a*)(R + base);
  float v0 = a.x + b.x, v1 = a.y + b.y, v2 = a.z + b.z, v3 = a.w + b.w;
  float s = v0 + v1 + v2 + v3;
  float q = v0 * v0 + v1 * v1 + v2 * v2 + v3 * v3;
#pragma unroll
  for (int o = 32; o > 0; o >>= 1) { s += __shfl_xor(s, o, 64); q += __shfl_xor(q, o, 64); }
  __shared__ float rs[4], rq[4];
  if (lane == 0) { rs[w] = s; rq[w] = q; }
  __syncthreads();
  s = rs[0] + rs[1] + rs[2] + rs[3];
  q = rq[0] + rq[1] + rq[2] + rq[3];
  const float mu = s * (1.f / 1024.f);
  const float var = q * (1.f / 1024.f) - mu * mu;
  const float rstd = rsqrtf(var + 1e-5f);
  float4 gv = *(const float4a*)(g + t * 4);
  float4 bv = *(const float4a*)(be + t * 4);
  float o0 = (v0 - mu) * rstd * gv.x + bv.x;
  float o1 = (v1 - mu) * rstd * gv.y + bv.y;
  float o2 = (v2 - mu) * rstd * gv.z + bv.z;
  float o3 = (v3 - mu) * rstd * gv.w + bv.w;
  float4 o4; o4.x = o0; o4.y = o1; o4.z = o2; o4.w = o3;
  *(float4a*)(Y + base) = o4;
  if (Yb) {
    ushort4 ob; ob.x = f2bf(o0); ob.y = f2bf(o1); ob.z = f2bf(o2); ob.w = f2bf(o3);
    *(ushort4a*)(Yb + base) = ob;
  }
}

extern "C" void kernel_launch(void* const* d_in, const int* in_sizes, int n_in,
                              void* d_out, int out_size, void* d_ws, size_t ws_size,
                              hipStream_t stream) {
  const float* x   = (const float*)d_in[0];
  const float* Wq  = (const float*)d_in[1];
  const float* bq  = (const float*)d_in[2];
  const float* Wk  = (const float*)d_in[3];
  const float* bk  = (const float*)d_in[4];
  const float* Wv  = (const float*)d_in[5];
  const float* bv  = (const float*)d_in[6];
  const float* W1  = (const float*)d_in[7];
  const float* b1  = (const float*)d_in[8];
  const float* g1  = (const float*)d_in[9];
  const float* be1 = (const float*)d_in[10];
  const float* W2  = (const float*)d_in[11];
  const float* b2  = (const float*)d_in[12];
  const float* g2  = (const float*)d_in[13];
  const float* be2 = (const float*)d_in[14];
  float* out = (float*)d_out;

  // ---- workspace layout (bytes). Peak 186,646,528 B (~178 MiB) - unchanged.
  const size_t NEED = 186646528ULL;
  if (ws_size < NEED) return;
  char* ws = (char*)d_ws;
  u16* xb  = (u16*)(ws + 0L);           // 16,777,216  [M][D]
  u16* Wqt = (u16*)(ws + 16777216L);    //  8,388,608  [H][D][D] transposed (e,d)
  u16* Wkt = (u16*)(ws + 25165824L);    //  8,388,608
  u16* Wvt = (u16*)(ws + 33554432L);    //  8,388,608
  u16* W1t = (u16*)(ws + 41943040L);    //  8,388,608  [D][H*D]  (out,in)
  u16* W2t = (u16*)(ws + 50331648L);    //  2,097,152  [D][D]    (out,in)
  u16* Qh  = (u16*)(ws + 52428800L);    // 16,777,216  [M][D] (per-head)
  u16* Kh  = (u16*)(ws + 69206016L);    // 16,777,216
  u16* Vt  = (u16*)(ws + 85983232L);    // 16,777,216  [B][D][S] (V transposed)
  u16* Ch  = (u16*)(ws + 102760448L);   // 16,777,216  per-head attn out [M][D]
  float* proj = (float*)(ws + 119537664L); // 33,554,432 f32, accumulated over heads
  u16* Sbh = (u16*)(ws + 153092096L);   // 33,554,432  [B][S][S] raw scores
  u16* Pb  = Qh;                        // 33,554,432  alias Qh+Kh (dead post-QK^T)
  float* y  = (float*)Qh;               // 33.5 MB f32 (Pb dead after PV)
  u16*   yb = Vt;                       // 16.8 MB bf16 (Vt dead after head loop)
  float* z2 = proj;                     // 33.5 MB f32 (proj dead after LN1)

  dim3 blk(256);
  // ---- convert x; transpose-convert all weights
  {
    long n4 = (long)M_ * D_ / 4;
    hipLaunchKernelGGL(cvt_f32_bf16, dim3(4096), blk, 0, stream, x, xb, n4);
  }
  hipLaunchKernelGGL(tcvt, dim3(32, 32, H_), blk, 0, stream, Wq, Wqt, D_, D_,
                     (long)D_ * D_, (long)D_ * D_);
  hipLaunchKernelGGL(tcvt, dim3(32, 32, H_), blk, 0, stream, Wk, Wkt, D_, D_,
                     (long)D_ * D_, (long)D_ * D_);
  hipLaunchKernelGGL(tcvt, dim3(32, 32, H_), blk, 0, stream, Wv, Wvt, D_, D_,
                     (long)D_ * D_, (long)D_ * D_);
  hipLaunchKernelGGL(tcvt, dim3(32, 128, 1), blk, 0, stream, W1, W1t, H_ * D_, D_, 0L, 0L);
  hipLaunchKernelGGL(tcvt, dim3(32, 32, 1), blk, 0, stream, W2, W2t, D_, D_, 0L, 0L);

  dim3 gproj(D_ / BN, M_ / BM, 1);           // 8 x 64
  dim3 gsc(S_ / BN, S_ / BM, B_);            // 16 x 16 x 4
  dim3 gpv(D_ / BN, S_ / BM, B_);            // 8 x 16 x 4

  for (int h = 0; h < H_; ++h) {
    const long wo = (long)h * D_ * D_;
    // Q/K: [M][D] bf16; V: straight to transposed [B][D][S]
    hipLaunchKernelGGL((gemm_bt<1, 1, 0>), gproj, blk, 0, stream,
                       xb, Wqt + wo, (void*)Qh, bq + (long)h * D_,
                       D_, D_, D_, D_, 0L, 0L, 0L, 1.0f);
    hipLaunchKernelGGL((gemm_bt<1, 1, 0>), gproj, blk, 0, stream,
                       xb, Wkt + wo, (void*)Kh, bk + (long)h * D_,
                       D_, D_, D_, D_, 0L, 0L, 0L, 1.0f);
    hipLaunchKernelGGL((gemm_bt<2, 1, 0>), gproj, blk, 0, stream,
                       xb, Wvt + wo, (void*)Vt, bv + (long)h * D_,
                       D_, D_, D_, D_, 0L, 0L, 0L, 1.0f);
    // scores: per b, Sbh[b] = Q[b] @ K[b]^T / 32
    hipLaunchKernelGGL((gemm_bt<1, 0, 0>), gsc, blk, 0, stream,
                       Qh, Kh, (void*)Sbh, (const float*)nullptr,
                       D_, D_, D_, S_, (long)S_ * D_, (long)S_ * D_, (long)S_ * S_, 0.03125f);
    // softmax rows: Pb = softmax(Sbh)
    hipLaunchKernelGGL(softmax2048, dim3(B_ * S_), blk, 0, stream, Sbh, Pb);
    // PV: Ch[b] = P[b] @ Vt[b]^T  (Vt rows are e, cols t -> B^T path)
    hipLaunchKernelGGL((gemm_bt<1, 0, 0>), gpv, blk, 0, stream,
                       Pb, Vt, (void*)Ch, (const float*)nullptr,
                       S_, S_, S_, D_, (long)S_ * S_, (long)D_ * S_, (long)S_ * D_, 1.0f);
    // proj (+)= Ch @ W1t[:, h*D:(h+1)*D]^T  (+ b1 on first head)
    if (h == 0) {
      hipLaunchKernelGGL((gemm_bt<0, 1, 0>), gproj, blk, 0, stream,
                         Ch, W1t + (long)h * D_, (void*)proj, b1,
                         D_, D_, H_ * D_, D_, 0L, 0L, 0L, 1.0f);
    } else {
      hipLaunchKernelGGL((gemm_bt<0, 0, 1>), gproj, blk, 0, stream,
                         Ch, W1t + (long)h * D_, (void*)proj, (const float*)nullptr,
                         D_, D_, H_ * D_, D_, 0L, 0L, 0L, 1.0f);
    }
  }

  // ---- LN1: y = LN(x + proj); also bf16 copy yb
  hipLaunchKernelGGL(ln_kernel, dim3(M_), blk, 0, stream, x, proj, g1, be1, y, yb);

  // ---- W2: z2 = yb @ W2t^T + b2 (f32)
  hipLaunchKernelGGL((gemm_bt<0, 1, 0>), gproj, blk, 0, stream,
                     yb, W2t, (void*)z2, b2, D_, D_, D_, D_, 0L, 0L, 0L, 1.0f);

  // ---- LN2: out = LN(y + z2)
  hipLaunchKernelGGL(ln_kernel, dim3(M_), blk, 0, stream, y, z2, g2, be2, out, (u16*)nullptr);
}

// Round 5
// 1018.343 us; speedup vs baseline: 2.2622x; 1.0288x over previous
//
#include <hip/hip_runtime.h>

using u16 = unsigned short;
using u32 = unsigned int;
typedef __attribute__((ext_vector_type(8))) short s16x8;
typedef __attribute__((ext_vector_type(4))) float f32x4;

typedef uint4   __attribute__((may_alias)) uint4a;
typedef ushort4 __attribute__((may_alias)) ushort4a;
typedef float4  __attribute__((may_alias)) float4a;
typedef u16     __attribute__((may_alias)) u16a;
typedef s16x8   __attribute__((may_alias)) s16x8a;

#define D_ 1024
#define H_ 4
#define B_ 4
#define S_ 2048
#define M_ 8192  /* B_*S_ */

__device__ __forceinline__ float bf2f(u16 u) { return __uint_as_float(((u32)u) << 16); }
__device__ __forceinline__ u16 f2bf(float f) {
  u32 b = __float_as_uint(f);
  return (u16)((b + 0x7fffu + ((b >> 16) & 1u)) >> 16);
}

__device__ __forceinline__ void gload_lds16(const u16* g, u16* l) {
  __builtin_amdgcn_global_load_lds(
      (const __attribute__((address_space(1))) void*)g,
      (__attribute__((address_space(3))) void*)l, 16, 0, 0);
}

#define FENCE asm volatile("" ::: "memory")
#define BAR do { FENCE; __builtin_amdgcn_s_barrier(); FENCE; } while (0)
#define VMC4 asm volatile("s_waitcnt vmcnt(4)" ::: "memory")

// ---------------- f32 -> bf16 convert ----------------
__global__ __launch_bounds__(256) void cvt_f32_bf16(const float* __restrict__ in,
                                                    u16* __restrict__ out, long n4) {
  long stride = (long)gridDim.x * blockDim.x;
  for (long i = (long)blockIdx.x * blockDim.x + threadIdx.x; i < n4; i += stride) {
    float4 v = ((const float4a*)in)[i];
    ushort4 o;
    o.x = f2bf(v.x); o.y = f2bf(v.y); o.z = f2bf(v.z); o.w = f2bf(v.w);
    ((ushort4a*)out)[i] = o;
  }
}

// ------------- transpose-convert: out[z][n][k] = bf16(in[z][k][n]) -------------
__global__ __launch_bounds__(256) void tcvt(const float* __restrict__ in,
                                            u16* __restrict__ out, int K, int N,
                                            long s_in, long s_out) {
  __shared__ float t[32][33];
  const int z = blockIdx.z;
  in += (long)z * s_in;
  out += (long)z * s_out;
  const int n0 = blockIdx.x * 32, k0 = blockIdx.y * 32;
  const int tx = threadIdx.x & 31, ty = threadIdx.x >> 5;
#pragma unroll
  for (int i = 0; i < 32; i += 8) t[ty + i][tx] = in[(long)(k0 + ty + i) * N + n0 + tx];
  __syncthreads();
#pragma unroll
  for (int i = 0; i < 32; i += 8)
    out[(long)(n0 + ty + i) * K + k0 + tx] = f2bf(t[tx][ty + i]);
}

// ================= 256x256 8-phase MFMA GEMM, B^T =================
// C[z] = A[z] @ B[z]^T * scale (+ bias) (+= C if ACC)
// A: [M,K] bf16 (lda). B: [N,K] bf16 (ldb). K % 128 == 0.
// LDS layout per buffer: 256 rows x 8 chunks of 16B; data chunk j of row r
// stored at chunk slot r*8 + (j ^ (r&7)). Staged linearly by global_load_lds
// with the inverse swizzle applied to the per-lane global source address.
__device__ __forceinline__ s16x8 lds_frag(const u16* buf, int r, int jc) {
  return *(const s16x8a*)&buf[(((r << 3) + (jc ^ (r & 7)))) << 3];
}

__device__ __forceinline__ void readB(const u16* Bbuf, int wc, int lane, s16x8 (&bfr)[4][2]) {
#pragma unroll
  for (int j = 0; j < 4; ++j)
#pragma unroll
    for (int s = 0; s < 2; ++s)
      bfr[j][s] = lds_frag(Bbuf, wc * 64 + j * 16 + (lane & 15), 4 * s + (lane >> 4));
}
__device__ __forceinline__ void readA(const u16* Abuf, int q, int wr, int lane, s16x8 (&afr)[2][2]) {
#pragma unroll
  for (int il = 0; il < 2; ++il)
#pragma unroll
    for (int s = 0; s < 2; ++s)
      afr[il][s] = lds_frag(Abuf, wr * 128 + (q * 2 + il) * 16 + (lane & 15), 4 * s + (lane >> 4));
}
__device__ __forceinline__ void mfma_quad(const s16x8 (&afr)[2][2], const s16x8 (&bfr)[4][2],
                                          f32x4 (&acc)[8][4], int q) {
  __builtin_amdgcn_s_setprio(1);
#pragma unroll
  for (int s = 0; s < 2; ++s)
#pragma unroll
    for (int il = 0; il < 2; ++il)
#pragma unroll
      for (int j = 0; j < 4; ++j)
        acc[q * 2 + il][j] =
            __builtin_amdgcn_mfma_f32_16x16x32_bf16(afr[il][s], bfr[j][s], acc[q * 2 + il][j], 0, 0, 0);
  __builtin_amdgcn_s_setprio(0);
}

template <int OUT_MODE, int HAS_BIAS, int ACC>
__global__ __launch_bounds__(512, 2) void gemm256(
    const u16* __restrict__ A, const u16* __restrict__ Bm, void* __restrict__ Cp,
    const float* __restrict__ bias, const float* __restrict__ bias2,
    int K, int lda, int ldb, int ldc, long sA, long sB, long sC, float scale) {
  __shared__ u16 Al[2][16384];
  __shared__ u16 Bl[2][16384];
  const int z = blockIdx.z;
  A += (long)z * sA;
  Bm += (long)z * sB;
  const long coff = (long)z * sC;
  const int bm = blockIdx.y * 256, bn = blockIdx.x * 256;
  const int tid = threadIdx.x;
  const int lane = tid & 63;
  const int w = tid >> 6;           // 0..7
  const int wr = w >> 2, wc = w & 3; // 2 x 4 wave grid; per-wave 128x64 output
  f32x4 acc[8][4] = {};
  const int nt2 = K >> 7;  // iterations; 2 K-tiles (of 64) each

  // stage one half-tile (128 rows x 64 k): this wave's 2 x gload_lds (16B/lane)
  auto stage = [&](const u16* src, int ld, int b0, u16* lbuf, int h, int kt) {
    const int k0 = kt << 6;
#pragma unroll
    for (int it = 0; it < 2; ++it) {
      int c = w * 128 + it * 64 + lane;
      int row = h * 128 + (c >> 3);
      int j = (c & 7) ^ (row & 7);  // inverse swizzle on global source
      gload_lds16(src + (long)(b0 + row) * ld + (k0 + j * 8),
                  lbuf + ((h * 1024 + w * 128 + it * 64) << 3));
    }
  };

  // ---- prologue: A0<-t0, B0<-t0, B1<-t1 (A1<-t1 staged at L1 of iter 0)
  stage(A, lda, bm, Al[0], 0, 0);
  stage(A, lda, bm, Al[0], 1, 0);
  stage(Bm, ldb, bn, Bl[0], 0, 0);
  stage(Bm, ldb, bn, Bl[0], 1, 0);
  stage(Bm, ldb, bn, Bl[1], 0, 1);
  stage(Bm, ldb, bn, Bl[1], 1, 1);
  VMC4;   // A0,B0 landed; B1 in flight
  BAR;

  s16x8 bfr[4][2];
  for (int i2 = 0; i2 < nt2; ++i2) {
    const int t = i2 * 2;
    s16x8 afr[2][2];
    // L1: compute t(q0) from buf0; stage A-buf1 <- t+1 lo
    readB(Bl[0], wc, lane, bfr);
    readA(Al[0], 0, wr, lane, afr);
    stage(A, lda, bm, Al[1], 0, t + 1);
    BAR;
    mfma_quad(afr, bfr, acc, 0);
    BAR;
    // L2
    readA(Al[0], 1, wr, lane, afr);
    stage(A, lda, bm, Al[1], 1, t + 1);
    BAR;
    mfma_quad(afr, bfr, acc, 1);
    BAR;
    // L3
    readA(Al[0], 2, wr, lane, afr);
    stage(Bm, ldb, bn, Bl[0], 0, t + 2);
    BAR;
    mfma_quad(afr, bfr, acc, 2);
    BAR;
    // L4  (+ counted vmcnt: tile t+1 fully landed before L5 reads)
    readA(Al[0], 3, wr, lane, afr);
    stage(Bm, ldb, bn, Bl[0], 1, t + 2);
    BAR;
    mfma_quad(afr, bfr, acc, 3);
    VMC4;
    BAR;
    // L5: compute t+1(q0) from buf1; stage A-buf0 <- t+2 lo
    readB(Bl[1], wc, lane, bfr);
    readA(Al[1], 0, wr, lane, afr);
    stage(A, lda, bm, Al[0], 0, t + 2);
    BAR;
    mfma_quad(afr, bfr, acc, 0);
    BAR;
    // L6
    readA(Al[1], 1, wr, lane, afr);
    stage(A, lda, bm, Al[0], 1, t + 2);
    BAR;
    mfma_quad(afr, bfr, acc, 1);
    BAR;
    // L7
    readA(Al[1], 2, wr, lane, afr);
    stage(Bm, ldb, bn, Bl[1], 0, t + 3);
    BAR;
    mfma_quad(afr, bfr, acc, 2);
    BAR;
    // L8  (+ counted vmcnt: tile t+2 fully landed before next L1 reads)
    readA(Al[1], 3, wr, lane, afr);
    stage(Bm, ldb, bn, Bl[1], 1, t + 3);
    BAR;
    mfma_quad(afr, bfr, acc, 3);
    VMC4;
    BAR;
  }

  // ---- epilogue: C/D layout col = lane&15, row = (lane>>4)*4 + reg
#pragma unroll
  for (int i = 0; i < 8; i++) {
    int mbase = bm + wr * 128 + i * 16 + ((lane >> 4) << 2);
#pragma unroll
    for (int j = 0; j < 4; j++) {
      int n = bn + wc * 64 + j * 16 + (lane & 15);
      float bv = 0.f;
      if (HAS_BIAS) {
        const float* bb = (z == 1 && bias2) ? bias2 : bias;
        bv = bb[n];
      }
#pragma unroll
      for (int r = 0; r < 4; r++) {
        float v = acc[i][j][r] * scale + bv;
        int mm = mbase + r;
        if (OUT_MODE == 2) {
          long idx = (long)(mm >> 11) * ((long)D_ * S_) + (long)n * S_ + (mm & 2047);
          ((u16a*)Cp)[idx] = f2bf(v);
        } else {
          long idx = coff + (long)mm * ldc + n;
          if (OUT_MODE == 1) {
            ((u16a*)Cp)[idx] = f2bf(v);
          } else {
            float* Cf = (float*)Cp;
            Cf[idx] = ACC ? (Cf[idx] + v) : v;
          }
        }
      }
    }
  }
}

// ---------------- row softmax over 2048 bf16, out of place ----------------
__global__ __launch_bounds__(256) void softmax2048(const u16* __restrict__ Sin,
                                                   u16* __restrict__ Pout) {
  const long row = blockIdx.x;
  const int t = threadIdx.x, lane = t & 63, w = t >> 6;
  uint4 raw = *(const uint4a*)(Sin + row * 2048 + t * 8);
  u16 u[8];
  u[0] = (u16)(raw.x & 0xffff); u[1] = (u16)(raw.x >> 16);
  u[2] = (u16)(raw.y & 0xffff); u[3] = (u16)(raw.y >> 16);
  u[4] = (u16)(raw.z & 0xffff); u[5] = (u16)(raw.z >> 16);
  u[6] = (u16)(raw.w & 0xffff); u[7] = (u16)(raw.w >> 16);
  float v[8], mx = -3.4e38f;
#pragma unroll
  for (int j = 0; j < 8; j++) { v[j] = bf2f(u[j]); mx = fmaxf(mx, v[j]); }
#pragma unroll
  for (int o = 32; o > 0; o >>= 1) mx = fmaxf(mx, __shfl_xor(mx, o, 64));
  __shared__ float red[4];
  if (lane == 0) red[w] = mx;
  __syncthreads();
  mx = fmaxf(fmaxf(red[0], red[1]), fmaxf(red[2], red[3]));
  float s = 0.f;
#pragma unroll
  for (int j = 0; j < 8; j++) { v[j] = __expf(v[j] - mx); s += v[j]; }
#pragma unroll
  for (int o = 32; o > 0; o >>= 1) s += __shfl_xor(s, o, 64);
  __syncthreads();
  if (lane == 0) red[w] = s;
  __syncthreads();
  float inv = 1.f / (red[0] + red[1] + red[2] + red[3]);
  uint4 ow;
  ow.x = f2bf(v[0] * inv) | ((u32)f2bf(v[1] * inv) << 16);
  ow.y = f2bf(v[2] * inv) | ((u32)f2bf(v[3] * inv) << 16);
  ow.z = f2bf(v[4] * inv) | ((u32)f2bf(v[5] * inv) << 16);
  ow.w = f2bf(v[6] * inv) | ((u32)f2bf(v[7] * inv) << 16);
  *(uint4a*)(Pout + row * 2048 + t * 8) = ow;
}

// ---------------- LayerNorm over 1024 ----------------
__global__ __launch_bounds__(256) void ln_kernel(
    const float* __restrict__ X, const float* __restrict__ R,
    const float* __restrict__ g, const float* __restrict__ be,
    float* __restrict__ Y, u16* __restrict__ Yb) {
  const long row = blockIdx.x;
  const int t = threadIdx.x, lane = t & 63, w = t >> 6;
  const long base = row * 1024 + t * 4;
  float4 a = *(const float4a*)(X + base);
  float4 b = *(const float4a*)(R + base);
  float v0 = a.x + b.x, v1 = a.y + b.y, v2 = a.z + b.z, v3 = a.w + b.w;
  float s = v0 + v1 + v2 + v3;
  float q = v0 * v0 + v1 * v1 + v2 * v2 + v3 * v3;
#pragma unroll
  for (int o = 32; o > 0; o >>= 1) { s += __shfl_xor(s, o, 64); q += __shfl_xor(q, o, 64); }
  __shared__ float rs[4], rq[4];
  if (lane == 0) { rs[w] = s; rq[w] = q; }
  __syncthreads();
  s = rs[0] + rs[1] + rs[2] + rs[3];
  q = rq[0] + rq[1] + rq[2] + rq[3];
  const float mu = s * (1.f / 1024.f);
  const float var = q * (1.f / 1024.f) - mu * mu;
  const float rstd = rsqrtf(var + 1e-5f);
  float4 gv = *(const float4a*)(g + t * 4);
  float4 bv = *(const float4a*)(be + t * 4);
  float o0 = (v0 - mu) * rstd * gv.x + bv.x;
  float o1 = (v1 - mu) * rstd * gv.y + bv.y;
  float o2 = (v2 - mu) * rstd * gv.z + bv.z;
  float o3 = (v3 - mu) * rstd * gv.w + bv.w;
  float4 o4; o4.x = o0; o4.y = o1; o4.z = o2; o4.w = o3;
  *(float4a*)(Y + base) = o4;
  if (Yb) {
    ushort4 ob; ob.x = f2bf(o0); ob.y = f2bf(o1); ob.z = f2bf(o2); ob.w = f2bf(o3);
    *(ushort4a*)(Yb + base) = ob;
  }
}

extern "C" void kernel_launch(void* const* d_in, const int* in_sizes, int n_in,
                              void* d_out, int out_size, void* d_ws, size_t ws_size,
                              hipStream_t stream) {
  const float* x   = (const float*)d_in[0];
  const float* Wq  = (const float*)d_in[1];
  const float* bq  = (const float*)d_in[2];
  const float* Wk  = (const float*)d_in[3];
  const float* bk  = (const float*)d_in[4];
  const float* Wv  = (const float*)d_in[5];
  const float* bv  = (const float*)d_in[6];
  const float* W1  = (const float*)d_in[7];
  const float* b1  = (const float*)d_in[8];
  const float* g1  = (const float*)d_in[9];
  const float* be1 = (const float*)d_in[10];
  const float* W2  = (const float*)d_in[11];
  const float* b2  = (const float*)d_in[12];
  const float* g2  = (const float*)d_in[13];
  const float* be2 = (const float*)d_in[14];
  float* out = (float*)d_out;

  // ---- workspace layout (bytes). Peak 186,646,528 B (~178 MiB).
  const size_t NEED = 186646528ULL;
  if (ws_size < NEED) return;
  char* ws = (char*)d_ws;
  u16* xb  = (u16*)(ws + 0L);           // 16,777,216  [M][D]
  u16* Wqt = (u16*)(ws + 16777216L);    //  8,388,608  [H][D][D] (out,in)
  u16* Wkt = (u16*)(ws + 25165824L);    //  8,388,608  (contiguous after Wqt)
  u16* Wvt = (u16*)(ws + 33554432L);    //  8,388,608
  u16* W1t = (u16*)(ws + 41943040L);    //  8,388,608  [D][H*D]
  u16* W2t = (u16*)(ws + 50331648L);    //  2,097,152  [D][D]
  u16* Qh  = (u16*)(ws + 52428800L);    // 16,777,216  [M][D]
  u16* Kh  = (u16*)(ws + 69206016L);    // 16,777,216  (contiguous after Qh)
  u16* Vt  = (u16*)(ws + 85983232L);    // 16,777,216  [B][D][S]
  u16* Ch  = (u16*)(ws + 102760448L);   // 16,777,216  [M][D]
  float* proj = (float*)(ws + 119537664L); // 33,554,432 f32
  u16* Sbh = (u16*)(ws + 153092096L);   // 33,554,432  [B][S][S]
  u16* Pb  = Qh;                        // alias Qh+Kh (dead post-QK^T)
  float* y  = (float*)Qh;               // f32 (after head loop)
  u16*   yb = Vt;                       // bf16 (Vt dead)
  float* z2 = proj;                     // f32 (proj dead after LN1)

  dim3 blk(256), blk512(512);
  {
    long n4 = (long)M_ * D_ / 4;
    hipLaunchKernelGGL(cvt_f32_bf16, dim3(4096), blk, 0, stream, x, xb, n4);
  }
  hipLaunchKernelGGL(tcvt, dim3(32, 32, H_), blk, 0, stream, Wq, Wqt, D_, D_,
                     (long)D_ * D_, (long)D_ * D_);
  hipLaunchKernelGGL(tcvt, dim3(32, 32, H_), blk, 0, stream, Wk, Wkt, D_, D_,
                     (long)D_ * D_, (long)D_ * D_);
  hipLaunchKernelGGL(tcvt, dim3(32, 32, H_), blk, 0, stream, Wv, Wvt, D_, D_,
                     (long)D_ * D_, (long)D_ * D_);
  hipLaunchKernelGGL(tcvt, dim3(32, 128, 1), blk, 0, stream, W1, W1t, H_ * D_, D_, 0L, 0L);
  hipLaunchKernelGGL(tcvt, dim3(32, 32, 1), blk, 0, stream, W2, W2t, D_, D_, 0L, 0L);

  for (int h = 0; h < H_; ++h) {
    const long wo = (long)h * D_ * D_;
    // Q and K in one launch: z=0 -> Q (Wqt, bq), z=1 -> K (Wkt, bk).
    // Wkt = Wqt + H*D*D; Kh = Qh + M*D (both contiguous by layout).
    hipLaunchKernelGGL((gemm256<1, 1, 0>), dim3(4, 32, 2), blk512, 0, stream,
                       xb, Wqt + wo, (void*)Qh, bq + (long)h * D_, bk + (long)h * D_,
                       D_, D_, D_, D_, 0L, (long)H_ * D_ * D_, (long)M_ * D_, 1.0f);
    // V straight to transposed [B][D][S]
    hipLaunchKernelGGL((gemm256<2, 1, 0>), dim3(4, 32, 1), blk512, 0, stream,
                       xb, Wvt + wo, (void*)Vt, bv + (long)h * D_, (const float*)nullptr,
                       D_, D_, D_, D_, 0L, 0L, 0L, 1.0f);
    // scores: per b, Sbh[b] = Q[b] @ K[b]^T / 32
    hipLaunchKernelGGL((gemm256<1, 0, 0>), dim3(8, 8, B_), blk512, 0, stream,
                       Qh, Kh, (void*)Sbh, (const float*)nullptr, (const float*)nullptr,
                       D_, D_, D_, S_, (long)S_ * D_, (long)S_ * D_, (long)S_ * S_, 0.03125f);
    // softmax rows: Pb = softmax(Sbh)
    hipLaunchKernelGGL(softmax2048, dim3(B_ * S_), blk, 0, stream, Sbh, Pb);
    // PV: Ch[b] = P[b] @ Vt[b]^T
    hipLaunchKernelGGL((gemm256<1, 0, 0>), dim3(4, 8, B_), blk512, 0, stream,
                       Pb, Vt, (void*)Ch, (const float*)nullptr, (const float*)nullptr,
                       S_, S_, S_, D_, (long)S_ * S_, (long)D_ * S_, (long)S_ * D_, 1.0f);
    // proj (+)= Ch @ W1t[:, h*D:(h+1)*D]^T
    if (h == 0) {
      hipLaunchKernelGGL((gemm256<0, 1, 0>), dim3(4, 32, 1), blk512, 0, stream,
                         Ch, W1t + (long)h * D_, (void*)proj, b1, (const float*)nullptr,
                         D_, D_, H_ * D_, D_, 0L, 0L, 0L, 1.0f);
    } else {
      hipLaunchKernelGGL((gemm256<0, 0, 1>), dim3(4, 32, 1), blk512, 0, stream,
                         Ch, W1t + (long)h * D_, (void*)proj, (const float*)nullptr,
                         (const float*)nullptr, D_, D_, H_ * D_, D_, 0L, 0L, 0L, 1.0f);
    }
  }

  // ---- LN1: y = LN(x + proj); also bf16 copy yb
  hipLaunchKernelGGL(ln_kernel, dim3(M_), blk, 0, stream, x, proj, g1, be1, y, yb);

  // ---- W2: z2 = yb @ W2t^T + b2 (f32)
  hipLaunchKernelGGL((gemm256<0, 1, 0>), dim3(4, 32, 1), blk512, 0, stream,
                     yb, W2t, (void*)z2, b2, (const float*)nullptr,
                     D_, D_, D_, D_, 0L, 0L, 0L, 1.0f);

  // ---- LN2: out = LN(y + z2)
  hipLaunchKernelGGL(ln_kernel, dim3(M_), blk, 0, stream, y, z2, g2, be2, out, (u16*)nullptr);
}

// Round 6
// 927.204 us; speedup vs baseline: 2.4846x; 1.0983x over previous
//
#include <hip/hip_runtime.h>

using u16 = unsigned short;
using u32 = unsigned int;
typedef __attribute__((ext_vector_type(8))) short s16x8;
typedef __attribute__((ext_vector_type(4))) float f32x4;

typedef uint4   __attribute__((may_alias)) uint4a;
typedef ushort4 __attribute__((may_alias)) ushort4a;
typedef float4  __attribute__((may_alias)) float4a;
typedef u16     __attribute__((may_alias)) u16a;
typedef s16x8   __attribute__((may_alias)) s16x8a;

#define D_ 1024
#define H_ 4
#define B_ 4
#define S_ 2048
#define M_ 8192  /* B_*S_ */

#define BM 128
#define BN 128
#define BK 32

__device__ __forceinline__ float bf2f(u16 u) { return __uint_as_float(((u32)u) << 16); }
__device__ __forceinline__ u16 f2bf(float f) {
  u32 b = __float_as_uint(f);
  return (u16)((b + 0x7fffu + ((b >> 16) & 1u)) >> 16);
}

__device__ __forceinline__ void gload_lds16(const u16* g, u16* l) {
  __builtin_amdgcn_global_load_lds(
      (const __attribute__((address_space(1))) void*)g,
      (__attribute__((address_space(3))) void*)l, 16, 0, 0);
}

// XCD-bijective swizzle + 4x4 quad decomposition, z folded into x-axis.
// Requires nwg%16==0, (gx*gz)%4==0, gy%4==0 (all our grids satisfy).
__device__ __forceinline__ void swz_decomp(int& x, int& y, int& z) {
  const int gx = gridDim.x, gy = gridDim.y;
  const int nwg = gx * gy * gridDim.z;
  const int flat = (blockIdx.z * gy + blockIdx.y) * gx + blockIdx.x;
  const int swz = (flat & 7) * (nwg >> 3) + (flat >> 3);
  const int t = swz >> 4, i = swz & 15;
  const int tiles_X = (gx * gridDim.z) >> 2;
  const int X = (t % tiles_X) * 4 + (i & 3);
  y = (t / tiles_X) * 4 + (i >> 2);
  z = X / gx;
  x = X % gx;
}

// ---------------- f32 -> bf16 convert ----------------
__global__ __launch_bounds__(256) void cvt_f32_bf16(const float* __restrict__ in,
                                                    u16* __restrict__ out, long n4) {
  long stride = (long)gridDim.x * blockDim.x;
  for (long i = (long)blockIdx.x * blockDim.x + threadIdx.x; i < n4; i += stride) {
    float4 v = ((const float4a*)in)[i];
    ushort4 o;
    o.x = f2bf(v.x); o.y = f2bf(v.y); o.z = f2bf(v.z); o.w = f2bf(v.w);
    ((ushort4a*)out)[i] = o;
  }
}

// ------------- transpose-convert: out[z][n][k] = bf16(in[z][k][n]) -------------
__global__ __launch_bounds__(256) void tcvt(const float* __restrict__ in,
                                            u16* __restrict__ out, int K, int N,
                                            long s_in, long s_out) {
  __shared__ float t[32][33];
  const int z = blockIdx.z;
  in += (long)z * s_in;
  out += (long)z * s_out;
  const int n0 = blockIdx.x * 32, k0 = blockIdx.y * 32;
  const int tx = threadIdx.x & 31, ty = threadIdx.x >> 5;
#pragma unroll
  for (int i = 0; i < 32; i += 8) t[ty + i][tx] = in[(long)(k0 + ty + i) * N + n0 + tx];
  __syncthreads();
#pragma unroll
  for (int i = 0; i < 32; i += 8)
    out[(long)(n0 + ty + i) * K + k0 + tx] = f2bf(t[tx][ty + i]);
}

// ------------- concat biases: o[0..4095]=bq, [4096..8191]=bk, [8192..12287]=bv ----
__global__ __launch_bounds__(256) void biascat(const float* __restrict__ bq,
                                               const float* __restrict__ bk,
                                               const float* __restrict__ bv,
                                               float* __restrict__ o) {
  int i = blockIdx.x * 256 + threadIdx.x;  // grid 48
  float v = (i < 4096) ? bq[i] : ((i < 8192) ? bk[i - 4096] : bv[i - 8192]);
  o[i] = v;
}

// ---------------- tiled MFMA GEMM, B^T only, 128x128 ----------------
// C[z] = A[z] @ B[z]^T * scale (+ bias[z*sBias + n]) (+= C if ACC)
// OUT_MODE: 0 = f32, 1 = bf16, 2 = bf16 transposed-per-batch
//           (idx = coff + (m>>11)*D*S + n*S + (m&2047)),
//           3 = QKV fused: z<2 -> bf16 normal, z==2 -> transposed.
__device__ __forceinline__ int lds_slot(int row, int ks) {
  return row * 4 + (ks ^ ((row >> 1) & 3));
}

template <int OUT_MODE, int HAS_BIAS, int ACC>
__global__ __launch_bounds__(256, 4) void gemm_bt(
    const u16* __restrict__ A, const u16* __restrict__ Bm, void* __restrict__ Cp,
    const float* __restrict__ bias, int K, int lda, int ldb, int ldc,
    long sA, long sB, long sC, long sBias, float scale) {
  __shared__ u16 Al[BM * BK];
  __shared__ u16 Bl[BN * BK];
  int bx, by, z;
  swz_decomp(bx, by, z);
  A += (long)z * sA;
  Bm += (long)z * sB;
  const long coff = (long)z * sC;
  const int bm = by * BM, bn = bx * BN;
  const int tid = threadIdx.x;
  const int lane = tid & 63;
  const int w = tid >> 6;
  const int wr = w >> 1, wc = w & 1;
  f32x4 acc[4][4] = {};

  for (int k0 = 0; k0 < K; k0 += BK) {
    __syncthreads();
#pragma unroll
    for (int it = 0; it < 2; ++it) {
      const int sbase = w * 128 + it * 64;
      const int slot = sbase + lane;
      const int row = slot >> 2;
      const int j = (slot & 3) ^ ((row >> 1) & 3);  // inverse swizzle on global src
      gload_lds16(A + (long)(bm + row) * lda + (k0 + j * 8), &Al[sbase * 8]);
      gload_lds16(Bm + (long)(bn + row) * ldb + (k0 + j * 8), &Bl[sbase * 8]);
    }
    __syncthreads();
    const int ks = lane >> 4;
    s16x8 a[4], b[4];
#pragma unroll
    for (int i = 0; i < 4; i++) {
      int row = wr * 64 + i * 16 + (lane & 15);
      a[i] = *(const s16x8a*)&Al[lds_slot(row, ks) * 8];
    }
#pragma unroll
    for (int j = 0; j < 4; j++) {
      int row = wc * 64 + j * 16 + (lane & 15);
      b[j] = *(const s16x8a*)&Bl[lds_slot(row, ks) * 8];
    }
#pragma unroll
    for (int i = 0; i < 4; i++)
#pragma unroll
      for (int j = 0; j < 4; j++)
        acc[i][j] = __builtin_amdgcn_mfma_f32_16x16x32_bf16(a[i], b[j], acc[i][j], 0, 0, 0);
  }

  // epilogue: C/D layout col = lane&15, row = (lane>>4)*4 + reg
  const bool tpose = (OUT_MODE == 2) || (OUT_MODE == 3 && z == 2);
#pragma unroll
  for (int i = 0; i < 4; i++) {
    int mbase = bm + wr * 64 + i * 16 + ((lane >> 4) << 2);
#pragma unroll
    for (int j = 0; j < 4; j++) {
      int n = bn + wc * 64 + j * 16 + (lane & 15);
      float bv = 0.f;
      if (HAS_BIAS) bv = bias[z * sBias + n];
      if (tpose) {
        ushort4 o;
        o.x = f2bf(acc[i][j][0] * scale + bv);
        o.y = f2bf(acc[i][j][1] * scale + bv);
        o.z = f2bf(acc[i][j][2] * scale + bv);
        o.w = f2bf(acc[i][j][3] * scale + bv);
        long idx = coff + (long)(mbase >> 11) * ((long)D_ * S_) + (long)n * S_ + (mbase & 2047);
        *(ushort4a*)&((u16a*)Cp)[idx] = o;
      } else {
#pragma unroll
        for (int r = 0; r < 4; r++) {
          float v = acc[i][j][r] * scale + bv;
          long idx = coff + (long)(mbase + r) * ldc + n;
          if (OUT_MODE == 1 || OUT_MODE == 3) {
            ((u16a*)Cp)[idx] = f2bf(v);
          } else {
            float* Cf = (float*)Cp;
            Cf[idx] = ACC ? (Cf[idx] + v) : v;
          }
        }
      }
    }
  }
}

// ---------------- row softmax over 2048 bf16, out of place ----------------
__global__ __launch_bounds__(256) void softmax2048(const u16* __restrict__ Sin,
                                                   u16* __restrict__ Pout) {
  const long row = blockIdx.x;
  const int t = threadIdx.x, lane = t & 63, w = t >> 6;
  uint4 raw = *(const uint4a*)(Sin + row * 2048 + t * 8);
  u16 u[8];
  u[0] = (u16)(raw.x & 0xffff); u[1] = (u16)(raw.x >> 16);
  u[2] = (u16)(raw.y & 0xffff); u[3] = (u16)(raw.y >> 16);
  u[4] = (u16)(raw.z & 0xffff); u[5] = (u16)(raw.z >> 16);
  u[6] = (u16)(raw.w & 0xffff); u[7] = (u16)(raw.w >> 16);
  float v[8], mx = -3.4e38f;
#pragma unroll
  for (int j = 0; j < 8; j++) { v[j] = bf2f(u[j]); mx = fmaxf(mx, v[j]); }
#pragma unroll
  for (int o = 32; o > 0; o >>= 1) mx = fmaxf(mx, __shfl_xor(mx, o, 64));
  __shared__ float red[4];
  if (lane == 0) red[w] = mx;
  __syncthreads();
  mx = fmaxf(fmaxf(red[0], red[1]), fmaxf(red[2], red[3]));
  float s = 0.f;
#pragma unroll
  for (int j = 0; j < 8; j++) { v[j] = __expf(v[j] - mx); s += v[j]; }
#pragma unroll
  for (int o = 32; o > 0; o >>= 1) s += __shfl_xor(s, o, 64);
  __syncthreads();
  if (lane == 0) red[w] = s;
  __syncthreads();
  float inv = 1.f / (red[0] + red[1] + red[2] + red[3]);
  uint4 ow;
  ow.x = f2bf(v[0] * inv) | ((u32)f2bf(v[1] * inv) << 16);
  ow.y = f2bf(v[2] * inv) | ((u32)f2bf(v[3] * inv) << 16);
  ow.z = f2bf(v[4] * inv) | ((u32)f2bf(v[5] * inv) << 16);
  ow.w = f2bf(v[6] * inv) | ((u32)f2bf(v[7] * inv) << 16);
  *(uint4a*)(Pout + row * 2048 + t * 8) = ow;
}

// ---------------- LayerNorm over 1024 ----------------
__global__ __launch_bounds__(256) void ln_kernel(
    const float* __restrict__ X, const float* __restrict__ R,
    const float* __restrict__ g, const float* __restrict__ be,
    float* __restrict__ Y, u16* __restrict__ Yb) {
  const long row = blockIdx.x;
  const int t = threadIdx.x, lane = t & 63, w = t >> 6;
  const long base = row * 1024 + t * 4;
  float4 a = *(const float4a*)(X + base);
  float4 b = *(const float4a*)(R + base);
  float v0 = a.x + b.x, v1 = a.y + b.y, v2 = a.z + b.z, v3 = a.w + b.w;
  float s = v0 + v1 + v2 + v3;
  float q = v0 * v0 + v1 * v1 + v2 * v2 + v3 * v3;
#pragma unroll
  for (int o = 32; o > 0; o >>= 1) { s += __shfl_xor(s, o, 64); q += __shfl_xor(q, o, 64); }
  __shared__ float rs[4], rq[4];
  if (lane == 0) { rs[w] = s; rq[w] = q; }
  __syncthreads();
  s = rs[0] + rs[1] + rs[2] + rs[3];
  q = rq[0] + rq[1] + rq[2] + rq[3];
  const float mu = s * (1.f / 1024.f);
  const float var = q * (1.f / 1024.f) - mu * mu;
  const float rstd = rsqrtf(var + 1e-5f);
  float4 gv = *(const float4a*)(g + t * 4);
  float4 bv = *(const float4a*)(be + t * 4);
  float o0 = (v0 - mu) * rstd * gv.x + bv.x;
  float o1 = (v1 - mu) * rstd * gv.y + bv.y;
  float o2 = (v2 - mu) * rstd * gv.z + bv.z;
  float o3 = (v3 - mu) * rstd * gv.w + bv.w;
  float4 o4; o4.x = o0; o4.y = o1; o4.z = o2; o4.w = o3;
  *(float4a*)(Y + base) = o4;
  if (Yb) {
    ushort4 ob; ob.x = f2bf(o0); ob.y = f2bf(o1); ob.z = f2bf(o2); ob.w = f2bf(o3);
    *(ushort4a*)(Yb + base) = ob;
  }
}

extern "C" void kernel_launch(void* const* d_in, const int* in_sizes, int n_in,
                              void* d_out, int out_size, void* d_ws, size_t ws_size,
                              hipStream_t stream) {
  const float* x   = (const float*)d_in[0];
  const float* Wq  = (const float*)d_in[1];
  const float* bq  = (const float*)d_in[2];
  const float* Wk  = (const float*)d_in[3];
  const float* bk  = (const float*)d_in[4];
  const float* Wv  = (const float*)d_in[5];
  const float* bv  = (const float*)d_in[6];
  const float* W1  = (const float*)d_in[7];
  const float* b1  = (const float*)d_in[8];
  const float* g1  = (const float*)d_in[9];
  const float* be1 = (const float*)d_in[10];
  const float* W2  = (const float*)d_in[11];
  const float* b2  = (const float*)d_in[12];
  const float* g2  = (const float*)d_in[13];
  const float* be2 = (const float*)d_in[14];
  float* out = (float*)d_out;

  // ---- workspace layout (bytes). Peak 186,646,528 B (~178 MiB).
  const size_t NEED = 186646528ULL;
  if (ws_size < NEED) return;
  char* ws = (char*)d_ws;
  u16* xb  = (u16*)(ws + 0L);           // 16,777,216  [M][D]
  u16* Wqt = (u16*)(ws + 16777216L);    //  8,388,608  [H][D][D] (out,in)
  u16* Wkt = (u16*)(ws + 25165824L);    //  8,388,608  (contiguous after Wqt)
  u16* Wvt = (u16*)(ws + 33554432L);    //  8,388,608  (contiguous after Wkt)
  u16* W1t = (u16*)(ws + 41943040L);    //  8,388,608  [D][H*D]
  u16* W2t = (u16*)(ws + 50331648L);    //  2,097,152  [D][D]
  u16* Qh  = (u16*)(ws + 52428800L);    // 16,777,216  [M][D]
  u16* Kh  = (u16*)(ws + 69206016L);    // 16,777,216  (Qh + M*D elems)
  u16* Vt  = (u16*)(ws + 85983232L);    // 16,777,216  [B][D][S] (Qh + 2*M*D elems)
  u16* Ch  = (u16*)(ws + 102760448L);   // 16,777,216  [M][D]
  float* proj = (float*)(ws + 119537664L); // 33,554,432 f32
  u16* Sbh = (u16*)(ws + 153092096L);   // 33,554,432  [B][S][S]
  u16* Pb  = Qh;                        // alias Qh+Kh (dead post-QK^T)
  float* y  = (float*)Qh;               // f32 (after head loop)
  u16*   yb = Vt;                       // bf16 (Vt dead)
  float* z2 = proj;                     // f32 (proj dead after LN1)
  float* biasQKV = out;                 // d_out as scratch: 48 KB, overwritten by LN2 later

  dim3 blk(256);
  {
    long n4 = (long)M_ * D_ / 4;
    hipLaunchKernelGGL(cvt_f32_bf16, dim3(4096), blk, 0, stream, x, xb, n4);
  }
  hipLaunchKernelGGL(tcvt, dim3(32, 32, H_), blk, 0, stream, Wq, Wqt, D_, D_,
                     (long)D_ * D_, (long)D_ * D_);
  hipLaunchKernelGGL(tcvt, dim3(32, 32, H_), blk, 0, stream, Wk, Wkt, D_, D_,
                     (long)D_ * D_, (long)D_ * D_);
  hipLaunchKernelGGL(tcvt, dim3(32, 32, H_), blk, 0, stream, Wv, Wvt, D_, D_,
                     (long)D_ * D_, (long)D_ * D_);
  hipLaunchKernelGGL(tcvt, dim3(32, 128, 1), blk, 0, stream, W1, W1t, H_ * D_, D_, 0L, 0L);
  hipLaunchKernelGGL(tcvt, dim3(32, 32, 1), blk, 0, stream, W2, W2t, D_, D_, 0L, 0L);
  hipLaunchKernelGGL(biascat, dim3(48), blk, 0, stream, bq, bk, bv, biasQKV);

  for (int h = 0; h < H_; ++h) {
    const long wo = (long)h * D_ * D_;
    // fused QKV for this head: z=0 Q, z=1 K (normal bf16), z=2 V (transposed)
    hipLaunchKernelGGL((gemm_bt<3, 1, 0>), dim3(8, 64, 3), blk, 0, stream,
                       xb, Wqt + wo, (void*)Qh, biasQKV + (long)h * D_,
                       D_, D_, D_, D_,
                       0L, (long)H_ * D_ * D_, (long)M_ * D_, (long)H_ * D_, 1.0f);
    // scores: per b, Sbh[b] = Q[b] @ K[b]^T / 32
    hipLaunchKernelGGL((gemm_bt<1, 0, 0>), dim3(16, 16, B_), blk, 0, stream,
                       Qh, Kh, (void*)Sbh, (const float*)nullptr,
                       D_, D_, D_, S_,
                       (long)S_ * D_, (long)S_ * D_, (long)S_ * S_, 0L, 0.03125f);
    // softmax rows: Pb = softmax(Sbh)
    hipLaunchKernelGGL(softmax2048, dim3(B_ * S_), blk, 0, stream, Sbh, Pb);
    // PV: Ch[b] = P[b] @ Vt[b]^T
    hipLaunchKernelGGL((gemm_bt<1, 0, 0>), dim3(8, 16, B_), blk, 0, stream,
                       Pb, Vt, (void*)Ch, (const float*)nullptr,
                       S_, S_, S_, D_,
                       (long)S_ * S_, (long)D_ * S_, (long)S_ * D_, 0L, 1.0f);
    // proj (+)= Ch @ W1t[:, h*D:(h+1)*D]^T
    if (h == 0) {
      hipLaunchKernelGGL((gemm_bt<0, 1, 0>), dim3(8, 64, 1), blk, 0, stream,
                         Ch, W1t + (long)h * D_, (void*)proj, b1,
                         D_, D_, H_ * D_, D_, 0L, 0L, 0L, 0L, 1.0f);
    } else {
      hipLaunchKernelGGL((gemm_bt<0, 0, 1>), dim3(8, 64, 1), blk, 0, stream,
                         Ch, W1t + (long)h * D_, (void*)proj, (const float*)nullptr,
                         D_, D_, H_ * D_, D_, 0L, 0L, 0L, 0L, 1.0f);
    }
  }

  // ---- LN1: y = LN(x + proj); also bf16 copy yb
  hipLaunchKernelGGL(ln_kernel, dim3(M_), blk, 0, stream, x, proj, g1, be1, y, yb);

  // ---- W2: z2 = yb @ W2t^T + b2 (f32)
  hipLaunchKernelGGL((gemm_bt<0, 1, 0>), dim3(8, 64, 1), blk, 0, stream,
                     yb, W2t, (void*)z2, b2, D_, D_, D_, D_, 0L, 0L, 0L, 0L, 1.0f);

  // ---- LN2: out = LN(y + z2)
  hipLaunchKernelGGL(ln_kernel, dim3(M_), blk, 0, stream, y, z2, g2, be2, out, (u16*)nullptr);
}

// Round 7
// 839.603 us; speedup vs baseline: 2.7438x; 1.1043x over previous
//
#include <hip/hip_runtime.h>

using u16 = unsigned short;
using u32 = unsigned int;
typedef __attribute__((ext_vector_type(8))) short s16x8;
typedef __attribute__((ext_vector_type(4))) float f32x4;

typedef uint4   __attribute__((may_alias)) uint4a;
typedef ushort4 __attribute__((may_alias)) ushort4a;
typedef float4  __attribute__((may_alias)) float4a;
typedef u16     __attribute__((may_alias)) u16a;
typedef s16x8   __attribute__((may_alias)) s16x8a;

#define D_ 1024
#define H_ 4
#define B_ 4
#define S_ 2048
#define M_ 8192  /* B_*S_ */

#define BM 128
#define BN 128
#define BK 32

__device__ __forceinline__ float bf2f(u16 u) { return __uint_as_float(((u32)u) << 16); }
__device__ __forceinline__ u16 f2bf(float f) {
  u32 b = __float_as_uint(f);
  return (u16)((b + 0x7fffu + ((b >> 16) & 1u)) >> 16);
}

__device__ __forceinline__ void gload_lds16(const u16* g, u16* l) {
  __builtin_amdgcn_global_load_lds(
      (const __attribute__((address_space(1))) void*)g,
      (__attribute__((address_space(3))) void*)l, 16, 0, 0);
}

// XCD-bijective swizzle + 4x4 quad decomposition, z folded into x-axis.
// Requires nwg%16==0, (gx*gz)%4==0, gy%4==0 (all our grids satisfy).
__device__ __forceinline__ void swz_decomp(int& x, int& y, int& z) {
  const int gx = gridDim.x, gy = gridDim.y;
  const int nwg = gx * gy * gridDim.z;
  const int flat = (blockIdx.z * gy + blockIdx.y) * gx + blockIdx.x;
  const int swz = (flat & 7) * (nwg >> 3) + (flat >> 3);
  const int t = swz >> 4, i = swz & 15;
  const int tiles_X = (gx * gridDim.z) >> 2;
  const int X = (t % tiles_X) * 4 + (i & 3);
  y = (t / tiles_X) * 4 + (i >> 2);
  z = X / gx;
  x = X % gx;
}

// ---------------- zero-fill f32 ----------------
__global__ __launch_bounds__(256) void zerof(float* __restrict__ p, int n) {
  int i = blockIdx.x * 256 + threadIdx.x;
  if (i < n) p[i] = 0.f;
}

// ---------------- f32 -> bf16 convert ----------------
__global__ __launch_bounds__(256) void cvt_f32_bf16(const float* __restrict__ in,
                                                    u16* __restrict__ out, long n4) {
  long stride = (long)gridDim.x * blockDim.x;
  for (long i = (long)blockIdx.x * blockDim.x + threadIdx.x; i < n4; i += stride) {
    float4 v = ((const float4a*)in)[i];
    ushort4 o;
    o.x = f2bf(v.x); o.y = f2bf(v.y); o.z = f2bf(v.z); o.w = f2bf(v.w);
    ((ushort4a*)out)[i] = o;
  }
}

// ------------- transpose-convert: out[z][n][k] = bf16(in[z][k][n]) -------------
__global__ __launch_bounds__(256) void tcvt(const float* __restrict__ in,
                                            u16* __restrict__ out, int K, int N,
                                            long s_in, long s_out) {
  __shared__ float t[32][33];
  const int z = blockIdx.z;
  in += (long)z * s_in;
  out += (long)z * s_out;
  const int n0 = blockIdx.x * 32, k0 = blockIdx.y * 32;
  const int tx = threadIdx.x & 31, ty = threadIdx.x >> 5;
#pragma unroll
  for (int i = 0; i < 32; i += 8) t[ty + i][tx] = in[(long)(k0 + ty + i) * N + n0 + tx];
  __syncthreads();
#pragma unroll
  for (int i = 0; i < 32; i += 8)
    out[(long)(n0 + ty + i) * K + k0 + tx] = f2bf(t[tx][ty + i]);
}

// ------------- concat biases ----
__global__ __launch_bounds__(256) void biascat(const float* __restrict__ bq,
                                               const float* __restrict__ bk,
                                               const float* __restrict__ bv,
                                               float* __restrict__ o) {
  int i = blockIdx.x * 256 + threadIdx.x;  // grid 48
  float v = (i < 4096) ? bq[i] : ((i < 8192) ? bk[i - 4096] : bv[i - 8192]);
  o[i] = v;
}

// ---------------- tiled MFMA GEMM, B^T only, 128x128 ----------------
// C[z] = A[z] @ B[z]^T * scale (+ bias[z*sBias + n]) (+= C if ACC)
// OUT_MODE: 0 = f32, 1 = bf16,
//           3 = QKV fused: z<2 bf16 normal, z==2 bf16 transposed-per-batch,
//           4 = scores: bf16 exp(acc*scale), + per-row f32 atomic rowsum -> drow
//           5 = PV: bf16 (acc * 1/drow[row])
__device__ __forceinline__ int lds_slot(int row, int ks) {
  return row * 4 + (ks ^ ((row >> 1) & 3));
}

template <int OUT_MODE, int HAS_BIAS, int ACC>
__global__ __launch_bounds__(256, 4) void gemm_bt(
    const u16* __restrict__ A, const u16* __restrict__ Bm, void* __restrict__ Cp,
    const float* __restrict__ bias, float* __restrict__ drow,
    int K, int lda, int ldb, int ldc,
    long sA, long sB, long sC, long sBias, float scale) {
  __shared__ u16 Al[BM * BK];
  __shared__ u16 Bl[BN * BK];
  int bx, by, z;
  swz_decomp(bx, by, z);
  A += (long)z * sA;
  Bm += (long)z * sB;
  const long coff = (long)z * sC;
  const int bm = by * BM, bn = bx * BN;
  const int tid = threadIdx.x;
  const int lane = tid & 63;
  const int w = tid >> 6;
  const int wr = w >> 1, wc = w & 1;
  f32x4 acc[4][4] = {};

  for (int k0 = 0; k0 < K; k0 += BK) {
    __syncthreads();
#pragma unroll
    for (int it = 0; it < 2; ++it) {
      const int sbase = w * 128 + it * 64;
      const int slot = sbase + lane;
      const int row = slot >> 2;
      const int j = (slot & 3) ^ ((row >> 1) & 3);  // inverse swizzle on global src
      gload_lds16(A + (long)(bm + row) * lda + (k0 + j * 8), &Al[sbase * 8]);
      gload_lds16(Bm + (long)(bn + row) * ldb + (k0 + j * 8), &Bl[sbase * 8]);
    }
    __syncthreads();
    const int ks = lane >> 4;
    s16x8 a[4], b[4];
#pragma unroll
    for (int i = 0; i < 4; i++) {
      int row = wr * 64 + i * 16 + (lane & 15);
      a[i] = *(const s16x8a*)&Al[lds_slot(row, ks) * 8];
    }
#pragma unroll
    for (int j = 0; j < 4; j++) {
      int row = wc * 64 + j * 16 + (lane & 15);
      b[j] = *(const s16x8a*)&Bl[lds_slot(row, ks) * 8];
    }
#pragma unroll
    for (int i = 0; i < 4; i++)
#pragma unroll
      for (int j = 0; j < 4; j++)
        acc[i][j] = __builtin_amdgcn_mfma_f32_16x16x32_bf16(a[i], b[j], acc[i][j], 0, 0, 0);
  }

  // epilogue: C/D layout col = lane&15, row = (lane>>4)*4 + reg
  if (OUT_MODE == 4) {
    // scores: write bf16 exp(acc*scale), accumulate per-row denominators
#pragma unroll
    for (int i = 0; i < 4; i++) {
      int mbase = bm + wr * 64 + i * 16 + ((lane >> 4) << 2);
#pragma unroll
      for (int r = 0; r < 4; r++) {
        const int mm = mbase + r;
        float rowsum = 0.f;
#pragma unroll
        for (int j = 0; j < 4; j++) {
          int n = bn + wc * 64 + j * 16 + (lane & 15);
          float e = __expf(acc[i][j][r] * scale);
          ((u16a*)Cp)[coff + (long)mm * ldc + n] = f2bf(e);
          rowsum += e;
        }
        rowsum += __shfl_xor(rowsum, 1, 64);
        rowsum += __shfl_xor(rowsum, 2, 64);
        rowsum += __shfl_xor(rowsum, 4, 64);
        rowsum += __shfl_xor(rowsum, 8, 64);
        if ((lane & 15) == 0) atomicAdd(&drow[(long)z * S_ + mm], rowsum);
      }
    }
    return;
  }
  if (OUT_MODE == 5) {
    // PV: divide by the row denominator
#pragma unroll
    for (int i = 0; i < 4; i++) {
      int mbase = bm + wr * 64 + i * 16 + ((lane >> 4) << 2);
      float inv[4];
#pragma unroll
      for (int r = 0; r < 4; r++) inv[r] = 1.0f / drow[(long)z * S_ + mbase + r];
#pragma unroll
      for (int j = 0; j < 4; j++) {
        int n = bn + wc * 64 + j * 16 + (lane & 15);
#pragma unroll
        for (int r = 0; r < 4; r++) {
          ((u16a*)Cp)[coff + (long)(mbase + r) * ldc + n] = f2bf(acc[i][j][r] * inv[r]);
        }
      }
    }
    return;
  }
  const bool tpose = (OUT_MODE == 3 && z == 2);
#pragma unroll
  for (int i = 0; i < 4; i++) {
    int mbase = bm + wr * 64 + i * 16 + ((lane >> 4) << 2);
#pragma unroll
    for (int j = 0; j < 4; j++) {
      int n = bn + wc * 64 + j * 16 + (lane & 15);
      float bv = 0.f;
      if (HAS_BIAS) bv = bias[z * sBias + n];
      if (tpose) {
        ushort4 o;
        o.x = f2bf(acc[i][j][0] * scale + bv);
        o.y = f2bf(acc[i][j][1] * scale + bv);
        o.z = f2bf(acc[i][j][2] * scale + bv);
        o.w = f2bf(acc[i][j][3] * scale + bv);
        long idx = coff + (long)(mbase >> 11) * ((long)D_ * S_) + (long)n * S_ + (mbase & 2047);
        *(ushort4a*)&((u16a*)Cp)[idx] = o;
      } else {
#pragma unroll
        for (int r = 0; r < 4; r++) {
          float v = acc[i][j][r] * scale + bv;
          long idx = coff + (long)(mbase + r) * ldc + n;
          if (OUT_MODE == 1 || OUT_MODE == 3) {
            ((u16a*)Cp)[idx] = f2bf(v);
          } else {
            float* Cf = (float*)Cp;
            Cf[idx] = ACC ? (Cf[idx] + v) : v;
          }
        }
      }
    }
  }
}

// ---------------- LayerNorm over 1024 ----------------
__global__ __launch_bounds__(256) void ln_kernel(
    const float* __restrict__ X, const float* __restrict__ R,
    const float* __restrict__ g, const float* __restrict__ be,
    float* __restrict__ Y, u16* __restrict__ Yb) {
  const long row = blockIdx.x;
  const int t = threadIdx.x, lane = t & 63, w = t >> 6;
  const long base = row * 1024 + t * 4;
  float4 a = *(const float4a*)(X + base);
  float4 b = *(const float4a*)(R + base);
  float v0 = a.x + b.x, v1 = a.y + b.y, v2 = a.z + b.z, v3 = a.w + b.w;
  float s = v0 + v1 + v2 + v3;
  float q = v0 * v0 + v1 * v1 + v2 * v2 + v3 * v3;
#pragma unroll
  for (int o = 32; o > 0; o >>= 1) { s += __shfl_xor(s, o, 64); q += __shfl_xor(q, o, 64); }
  __shared__ float rs[4], rq[4];
  if (lane == 0) { rs[w] = s; rq[w] = q; }
  __syncthreads();
  s = rs[0] + rs[1] + rs[2] + rs[3];
  q = rq[0] + rq[1] + rq[2] + rq[3];
  const float mu = s * (1.f / 1024.f);
  const float var = q * (1.f / 1024.f) - mu * mu;
  const float rstd = rsqrtf(var + 1e-5f);
  float4 gv = *(const float4a*)(g + t * 4);
  float4 bv = *(const float4a*)(be + t * 4);
  float o0 = (v0 - mu) * rstd * gv.x + bv.x;
  float o1 = (v1 - mu) * rstd * gv.y + bv.y;
  float o2 = (v2 - mu) * rstd * gv.z + bv.z;
  float o3 = (v3 - mu) * rstd * gv.w + bv.w;
  float4 o4; o4.x = o0; o4.y = o1; o4.z = o2; o4.w = o3;
  *(float4a*)(Y + base) = o4;
  if (Yb) {
    ushort4 ob; ob.x = f2bf(o0); ob.y = f2bf(o1); ob.z = f2bf(o2); ob.w = f2bf(o3);
    *(ushort4a*)(Yb + base) = ob;
  }
}

extern "C" void kernel_launch(void* const* d_in, const int* in_sizes, int n_in,
                              void* d_out, int out_size, void* d_ws, size_t ws_size,
                              hipStream_t stream) {
  const float* x   = (const float*)d_in[0];
  const float* Wq  = (const float*)d_in[1];
  const float* bq  = (const float*)d_in[2];
  const float* Wk  = (const float*)d_in[3];
  const float* bk  = (const float*)d_in[4];
  const float* Wv  = (const float*)d_in[5];
  const float* bv  = (const float*)d_in[6];
  const float* W1  = (const float*)d_in[7];
  const float* b1  = (const float*)d_in[8];
  const float* g1  = (const float*)d_in[9];
  const float* be1 = (const float*)d_in[10];
  const float* W2  = (const float*)d_in[11];
  const float* b2  = (const float*)d_in[12];
  const float* g2  = (const float*)d_in[13];
  const float* be2 = (const float*)d_in[14];
  float* out = (float*)d_out;

  // ---- workspace layouts.
  // base (fallback): peak 186,646,528 B. Cc path: peak 203,423,744 B.
  const size_t NEED_BASE = 186646528ULL;
  const size_t NEED_CC   = 203423744ULL;
  if (ws_size < NEED_BASE) return;
  const bool useCc = (ws_size >= NEED_CC);
  char* ws = (char*)d_ws;
  u16* xb  = (u16*)(ws + 0L);           // 16,777,216  [M][D]
  u16* Wqt = (u16*)(ws + 16777216L);    //  8,388,608  [H][D][D] (out,in)
  u16* Wkt = (u16*)(ws + 25165824L);    //  8,388,608
  u16* Wvt = (u16*)(ws + 33554432L);    //  8,388,608
  u16* W1t = (u16*)(ws + 41943040L);    //  8,388,608  [D][H*D]
  u16* W2t = (u16*)(ws + 50331648L);    //  2,097,152  [D][D]
  u16* Qh  = (u16*)(ws + 52428800L);    // 16,777,216  [M][D]
  u16* Kh  = (u16*)(ws + 69206016L);    // 16,777,216
  u16* Vt  = (u16*)(ws + 85983232L);    // 16,777,216  [B][D][S]
  u16* Sbh = (u16*)(ws + 102760448L);   // 33,554,432  [B][S][S] exp-scores
  // Cc path: Cc at 136,314,880 (67,108,864); proj aliases Sbh; z2 aliases Cc.
  // fallback: Ch at 136,314,880 (16.8MB); proj at 153,092,096 (33.5MB); z2=proj.
  u16* Cc   = (u16*)(ws + 136314880L);
  u16* Ch   = (u16*)(ws + 136314880L);
  float* proj = useCc ? (float*)Sbh : (float*)(ws + 153092096L);
  float* y  = (float*)Qh;               // f32 33.5MB (Qh+Kh dead after head loop)
  u16*   yb = Vt;                       // bf16 (Vt dead)
  float* z2 = useCc ? (float*)Cc : proj;
  float* biasQKV = out;                 // d_out scratch: [0,12288) floats
  float* dsum = out + 16384;            // [H][B][S] f32 = 32768 floats

  dim3 blk(256);
  {
    long n4 = (long)M_ * D_ / 4;
    hipLaunchKernelGGL(cvt_f32_bf16, dim3(4096), blk, 0, stream, x, xb, n4);
  }
  hipLaunchKernelGGL(tcvt, dim3(32, 32, H_), blk, 0, stream, Wq, Wqt, D_, D_,
                     (long)D_ * D_, (long)D_ * D_);
  hipLaunchKernelGGL(tcvt, dim3(32, 32, H_), blk, 0, stream, Wk, Wkt, D_, D_,
                     (long)D_ * D_, (long)D_ * D_);
  hipLaunchKernelGGL(tcvt, dim3(32, 32, H_), blk, 0, stream, Wv, Wvt, D_, D_,
                     (long)D_ * D_, (long)D_ * D_);
  hipLaunchKernelGGL(tcvt, dim3(32, 128, 1), blk, 0, stream, W1, W1t, H_ * D_, D_, 0L, 0L);
  hipLaunchKernelGGL(tcvt, dim3(32, 32, 1), blk, 0, stream, W2, W2t, D_, D_, 0L, 0L);
  hipLaunchKernelGGL(biascat, dim3(48), blk, 0, stream, bq, bk, bv, biasQKV);
  hipLaunchKernelGGL(zerof, dim3(128), blk, 0, stream, dsum, H_ * B_ * S_);

  for (int h = 0; h < H_; ++h) {
    const long wo = (long)h * D_ * D_;
    float* dh = dsum + (long)h * B_ * S_;
    // fused QKV: z=0 Q, z=1 K (normal), z=2 V (transposed)
    hipLaunchKernelGGL((gemm_bt<3, 1, 0>), dim3(8, 64, 3), blk, 0, stream,
                       xb, Wqt + wo, (void*)Qh, biasQKV + (long)h * D_, (float*)nullptr,
                       D_, D_, D_, D_,
                       0L, (long)H_ * D_ * D_, (long)M_ * D_, (long)H_ * D_, 1.0f);
    // scores: Sbh[b] = exp(Q K^T / 32), rowsums -> dh
    hipLaunchKernelGGL((gemm_bt<4, 0, 0>), dim3(16, 16, B_), blk, 0, stream,
                       Qh, Kh, (void*)Sbh, (const float*)nullptr, dh,
                       D_, D_, D_, S_,
                       (long)S_ * D_, (long)S_ * D_, (long)S_ * S_, 0L, 0.03125f);
    // PV with row-normalize epilogue
    if (useCc) {
      // write into concat layout Cc[b*S+s][h*D + e]
      hipLaunchKernelGGL((gemm_bt<5, 0, 0>), dim3(8, 16, B_), blk, 0, stream,
                         Sbh, Vt, (void*)(Cc + (long)h * D_), (const float*)nullptr, dh,
                         S_, S_, S_, H_ * D_,
                         (long)S_ * S_, (long)D_ * S_, (long)S_ * H_ * D_, 0L, 1.0f);
    } else {
      hipLaunchKernelGGL((gemm_bt<5, 0, 0>), dim3(8, 16, B_), blk, 0, stream,
                         Sbh, Vt, (void*)Ch, (const float*)nullptr, dh,
                         S_, S_, S_, D_,
                         (long)S_ * S_, (long)D_ * S_, (long)S_ * D_, 0L, 1.0f);
      // proj (+)= Ch @ W1t[:, h*D:(h+1)*D]^T
      if (h == 0) {
        hipLaunchKernelGGL((gemm_bt<0, 1, 0>), dim3(8, 64, 1), blk, 0, stream,
                           Ch, W1t + (long)h * D_, (void*)proj, b1, (float*)nullptr,
                           D_, D_, H_ * D_, D_, 0L, 0L, 0L, 0L, 1.0f);
      } else {
        hipLaunchKernelGGL((gemm_bt<0, 0, 1>), dim3(8, 64, 1), blk, 0, stream,
                           Ch, W1t + (long)h * D_, (void*)proj, (const float*)nullptr,
                           (float*)nullptr, D_, D_, H_ * D_, D_, 0L, 0L, 0L, 0L, 1.0f);
      }
    }
  }

  if (useCc) {
    // single W1: proj = Cc @ W1t^T + b1, K = 4096
    hipLaunchKernelGGL((gemm_bt<0, 1, 0>), dim3(8, 64, 1), blk, 0, stream,
                       Cc, W1t, (void*)proj, b1, (float*)nullptr,
                       H_ * D_, H_ * D_, H_ * D_, D_, 0L, 0L, 0L, 0L, 1.0f);
  }

  // ---- LN1: y = LN(x + proj); also bf16 copy yb
  hipLaunchKernelGGL(ln_kernel, dim3(M_), blk, 0, stream, x, proj, g1, be1, y, yb);

  // ---- W2: z2 = yb @ W2t^T + b2 (f32)
  hipLaunchKernelGGL((gemm_bt<0, 1, 0>), dim3(8, 64, 1), blk, 0, stream,
                     yb, W2t, (void*)z2, b2, (float*)nullptr,
                     D_, D_, D_, D_, 0L, 0L, 0L, 0L, 1.0f);

  // ---- LN2: out = LN(y + z2)
  hipLaunchKernelGGL(ln_kernel, dim3(M_), blk, 0, stream, y, z2, g2, be2, out, (u16*)nullptr);
}